// Round 10
// baseline (298.583 us; speedup 1.0000x reference)
//
#include <hip/hip_runtime.h>
#include <hip/hip_fp16.h>

#define B_ 2
#define CX 64
#define HH 192
#define WW 192
#define HW (HH*WW)
#define HS 48
#define WS 48
#define HWS (HS*WS)
#define CE 160
#define C4 432
#define DG_ 16
#define COUT_D 128

typedef short bf16x8 __attribute__((ext_vector_type(8)));
typedef _Float16 f16x8 __attribute__((ext_vector_type(8)));
typedef float f32x4 __attribute__((ext_vector_type(4)));
typedef unsigned short u16;

__device__ __forceinline__ unsigned f2bf(float f) {
    unsigned u = __float_as_uint(f);
    return (u + 0x7FFFu + ((u >> 16) & 1u)) >> 16;   // RNE
}
__device__ __forceinline__ float bf2f(u16 h) {
    return __uint_as_float(((unsigned)h) << 16);
}
__device__ __forceinline__ void split_hl(float v, u16& h, u16& l) {
    h = (u16)f2bf(v);
    l = (u16)f2bf(v - bf2f(h));
}
__device__ __forceinline__ float tanh_fast(float v) {
    float e = __expf(2.f * v);
    return 1.f - 2.f * __builtin_amdgcn_rcpf(e + 1.f);
}
__device__ __forceinline__ float sigmoid_fast(float s) {
    return __builtin_amdgcn_rcpf(1.f + __expf(-s));
}

// ---------------- fused prep: zp + wq1..wq4 + wA ----------------
__device__ __forceinline__ void prep_wq_body(const float* __restrict__ w, u16* __restrict__ wq,
                                             int i, int OC, int OCP, int CIN) {
    int ic = i % CIN; int rest = i / CIN;
    int oc = rest % OCP; rest /= OCP;
    int q = rest % 9; int kind = rest / 9;
    float v = (oc < OC) ? w[((size_t)oc * CIN + ic) * 9 + q] : 0.f;
    u16 h, l; split_hl(v, h, l);
    wq[i] = kind ? l : h;
}

__global__ void fused_prep_kernel(const float* __restrict__ w1, const float* __restrict__ w2,
                                  const float* __restrict__ w3, const float* __restrict__ w4,
                                  const float* __restrict__ wgt,
                                  float* __restrict__ zp, u16* __restrict__ wq1,
                                  u16* __restrict__ wq2, u16* __restrict__ wq3,
                                  u16* __restrict__ wq4, u16* __restrict__ wA) {
    int bid = blockIdx.x, t = threadIdx.x;
    if (bid == 0) { zp[t] = 0.f; return; }
    if (bid < 721)  { prep_wq_body(w1, wq1, (bid - 1) * 256 + t, 64, 64, 160); return; }
    if (bid < 1009) { prep_wq_body(w2, wq2, (bid - 721) * 256 + t, 64, 64, 64); return; }
    if (bid < 1297) { prep_wq_body(w3, wq3, (bid - 1009) * 256 + t, 64, 64, 64); return; }
    if (bid < 3313) { prep_wq_body(w4, wq4, (bid - 1297) * 256 + t, 432, 448, 64); return; }
    // wA fp16: [o][g*96 + tap*8 + c], taps 9..11 = 0
    int i = (bid - 3313) * 256 + t;                  // 128*1536 = 768*256
    int o = i / 1536, col = i - o * 1536;
    int g = col / 96, r = col - g * 96;
    int tap = r >> 3, c = r & 7;
    float v = (tap < 9) ? wgt[(size_t)o * 1152 + (g * 8 + c) * 9 + tap] : 0.f;
    wA[i] = __half_as_ushort(__float2half_rn(v));
}

// ---------------- fused: x/addf -> NHWC fp16 xg ; avgpool4+concat -> pool_t ----------------
__global__ void fused_trans_pool_kernel(const float* __restrict__ x, const float* __restrict__ flow,
                                        const float* __restrict__ addf,
                                        u16* __restrict__ xg, u16* __restrict__ pt) {
    int bid = blockIdx.x, t = threadIdx.x;
    if (bid < 4608) {
        int i = bid * 256 + t;                       // 2*16*36864
        int p = i % HW;
        int g = (i / HW) % DG_;
        int b = i / (HW * DG_);
        const float* xb = x    + ((size_t)(b * CX + g * 4)) * HW + p;
        const float* ab = addf + ((size_t)(b * CX + g * 4)) * HW + p;
        __half2 h[4];
        h[0].x = __float2half_rn(xb[0]);      h[0].y = __float2half_rn(xb[HW]);
        h[1].x = __float2half_rn(xb[2 * HW]); h[1].y = __float2half_rn(xb[3 * HW]);
        h[2].x = __float2half_rn(ab[0]);      h[2].y = __float2half_rn(ab[HW]);
        h[3].x = __float2half_rn(ab[2 * HW]); h[3].y = __float2half_rn(ab[3 * HW]);
        *reinterpret_cast<uint4*>(&xg[(size_t)i * 8]) = *reinterpret_cast<uint4*>(h);
    } else {
        int i = (bid - 4608) * 256 + t;              // 737280
        int xs = i % WS, ys = (i / WS) % HS, c = (i / HWS) % CE, b = i / (HWS * CE);
        const float* src;
        if (c < 64)      src = x    + (size_t)(b * 64 + c) * HW;
        else if (c < 96) src = flow + (size_t)(b * 32 + (c - 64)) * HW;
        else             src = addf + (size_t)(b * 64 + (c - 96)) * HW;
        const float4* s4 = reinterpret_cast<const float4*>(src + (ys * 4) * WW + xs * 4);
        float sum = 0.f;
#pragma unroll
        for (int r = 0; r < 4; ++r) {
            float4 v = s4[r * (WW / 4)];
            sum += v.x + v.y + v.z + v.w;
        }
        float v = sum * (1.f / 16.f);
        u16 h, l; split_hl(v, h, l);
        size_t base = ((size_t)(b * HWS + ys * WS + xs) * 2) * CE + c;
        pt[base] = h; pt[base + CE] = l;
    }
}

// ---------------- 4-way K-split MFMA 3x3 conv (64 oc), 16 waves: 4 ocgrp x 4 ksplit ----------------
template<int CIN, int U0, int U1, int U2, int UT, bool LRELU>
__global__ __launch_bounds__(1024) void conv_ks(const u16* __restrict__ in_t,
                                                const u16* __restrict__ wq,
                                                const float* __restrict__ bias,
                                                u16* __restrict__ out_t,
                                                const float* __restrict__ zp) {
    __shared__ float red[3 * 4 * 256];               // [ks-1][ocgrp][r*64+lane]
    const int t = threadIdx.x;
    const int w = t >> 6;
    const int ocgrp = w & 3, ks = w >> 2;
    const int lane = t & 63;
    const int l15 = t & 15, l4 = (t >> 4) & 3;
    const int tile = blockIdx.x;
    const int ty0 = (tile / 12) * 4, tx0 = (tile % 12) * 4;
    const int b = blockIdx.z;
    const int ocb = ocgrp * 16;
    const int py = ty0 + (l15 >> 2), pxx = tx0 + (l15 & 3);
    f32x4 ahh = {0,0,0,0}, ahl = {0,0,0,0}, alh = {0,0,0,0};
    const u16* inb = in_t + (size_t)b * (HWS * 2 * CIN);
    const u16* zp16 = (const u16*)zp;
    constexpr int KB = CIN / 32;

#define CONV_BODY(US, UE)                                                             \
    _Pragma("unroll")                                                                 \
    for (int u = (US); u < (UE); ++u) {                                               \
        const int q = u / KB, kb = u % KB;                                            \
        int sy = py + q / 3 - 1, sx = pxx + q % 3 - 1;                                \
        bool valid = ((unsigned)sy < 48u) && ((unsigned)sx < 48u);                    \
        const u16* bh = valid ? inb + ((size_t)(sy * 48 + sx) * 2) * CIN : zp16;      \
        const u16* bl = valid ? inb + ((size_t)(sy * 48 + sx) * 2 + 1) * CIN : zp16;  \
        const u16* wh = wq + ((size_t)q * 64 + ocb + l15) * CIN + l4 * 8 + kb * 32;   \
        const u16* wl = wh + (size_t)9 * 64 * CIN;                                    \
        bf16x8 Ah = *reinterpret_cast<const bf16x8*>(wh);                             \
        bf16x8 Al = *reinterpret_cast<const bf16x8*>(wl);                             \
        bf16x8 Bh = *reinterpret_cast<const bf16x8*>(bh + kb * 32 + l4 * 8);          \
        bf16x8 Bl = *reinterpret_cast<const bf16x8*>(bl + kb * 32 + l4 * 8);          \
        ahh = __builtin_amdgcn_mfma_f32_16x16x32_bf16(Ah, Bh, ahh, 0, 0, 0);          \
        ahl = __builtin_amdgcn_mfma_f32_16x16x32_bf16(Ah, Bl, ahl, 0, 0, 0);          \
        alh = __builtin_amdgcn_mfma_f32_16x16x32_bf16(Al, Bh, alh, 0, 0, 0);          \
    }
    if (ks == 0)      { CONV_BODY(0,  U0) }
    else if (ks == 1) { CONV_BODY(U0, U1) }
    else if (ks == 2) { CONV_BODY(U1, U2) }
    else              { CONV_BODY(U2, UT) }
#undef CONV_BODY

    float vsum[4];
#pragma unroll
    for (int r = 0; r < 4; ++r) vsum[r] = ahh[r] + ahl[r] + alh[r];
    if (ks) {
#pragma unroll
        for (int r = 0; r < 4; ++r)
            red[((ks - 1) * 4 + ocgrp) * 256 + r * 64 + lane] = vsum[r];
    }
    __syncthreads();
    if (!ks) {
#pragma unroll
        for (int r = 0; r < 4; ++r) {
#pragma unroll
            for (int j = 0; j < 3; ++j)
                vsum[r] += red[(j * 4 + ocgrp) * 256 + r * 64 + lane];
            int oc = ocb + l4 * 4 + r;
            float v = vsum[r] + bias[oc];
            if (LRELU) v = (v >= 0.f) ? v : 0.2f * v;
            u16 h, l; split_hl(v, h, l);
            size_t base = ((size_t)(b * HWS + py * 48 + pxx) * 2) * 64 + oc;
            out_t[base] = h; out_t[base + 64] = l;
        }
    }
}

// ---------------- MFMA 3x3 conv (conv4: 432 oc, f32 out), 4 waves ----------------
template<int CIN, int OC, int OCP, bool LRELU>
__global__ __launch_bounds__(256) void conv_mfma(const u16* __restrict__ in_t,
                                                 const u16* __restrict__ wq,
                                                 const float* __restrict__ bias,
                                                 float* __restrict__ out_f,
                                                 const float* __restrict__ zp) {
    const int t = threadIdx.x;
    const int wv = __builtin_amdgcn_readfirstlane(t >> 6);
    const int l15 = t & 15, l4 = (t >> 4) & 3;
    const int tile = blockIdx.x;
    const int ty0 = (tile / 12) * 4, tx0 = (tile % 12) * 4;
    const int ocb = blockIdx.y * 64 + wv * 16;
    const int b = blockIdx.z;
    const int py = ty0 + (l15 >> 2), pxx = tx0 + (l15 & 3);
    f32x4 ahh = {0,0,0,0}, ahl = {0,0,0,0}, alh = {0,0,0,0};
    const u16* inb = in_t + (size_t)b * (HWS * 2 * CIN);
    const u16* zp16 = (const u16*)zp;
#pragma unroll
    for (int q = 0; q < 9; ++q) {
        int sy = py + q / 3 - 1, sx = pxx + q % 3 - 1;
        bool valid = ((unsigned)sy < 48u) && ((unsigned)sx < 48u);
        const u16* bh = valid ? inb + ((size_t)(sy * 48 + sx) * 2) * CIN : zp16;
        const u16* bl = valid ? inb + ((size_t)(sy * 48 + sx) * 2 + 1) * CIN : zp16;
        const u16* wh = wq + ((size_t)q * OCP + ocb + l15) * CIN + l4 * 8;
        const u16* wl = wq + ((size_t)(9 + q) * OCP + ocb + l15) * CIN + l4 * 8;
#pragma unroll
        for (int kb = 0; kb < CIN / 32; ++kb) {
            bf16x8 Ah = *reinterpret_cast<const bf16x8*>(wh + kb * 32);
            bf16x8 Al = *reinterpret_cast<const bf16x8*>(wl + kb * 32);
            bf16x8 Bh = *reinterpret_cast<const bf16x8*>(bh + kb * 32 + l4 * 8);
            bf16x8 Bl = *reinterpret_cast<const bf16x8*>(bl + kb * 32 + l4 * 8);
            ahh = __builtin_amdgcn_mfma_f32_16x16x32_bf16(Ah, Bh, ahh, 0, 0, 0);
            ahl = __builtin_amdgcn_mfma_f32_16x16x32_bf16(Ah, Bl, ahl, 0, 0, 0);
            alh = __builtin_amdgcn_mfma_f32_16x16x32_bf16(Al, Bh, alh, 0, 0, 0);
        }
    }
#pragma unroll
    for (int r = 0; r < 4; ++r) {
        int oc = ocb + l4 * 4 + r;
        float v = ahh[r] + ahl[r] + alh[r] + ((oc < OC) ? bias[oc] : 0.f);
        if (LRELU) v = (v >= 0.f) ? v : 0.2f * v;
        if (oc < OC) out_f[((size_t)(b * OC + oc)) * HWS + py * 48 + pxx] = v;
    }
}

// ---------------- deform v10: R9 barrier skeleton, 256 threads / 4 waves x 32oc,
// PH12 2.25 items/thread (ILP), setprio + XCD swizzle kept ----------------
__global__ __launch_bounds__(256) void deform_mfma(
    const u16* __restrict__ xg, const float* __restrict__ flow,
    const float* __restrict__ a4, const u16* __restrict__ wA,
    const float* __restrict__ bias, float* __restrict__ out)
{
    __shared__ u16 val[2][64 * 104];                 // fp16 [pixel][ck pad 96->104]
    __shared__ float a4t[2][27 * 16];
    __shared__ float flds[2][128];
    __shared__ float rw[4][64];
    __shared__ int rb[64];
    const int t = threadIdx.x;
    // XCD-aware swizzle: 576 = 8 * 72 -> each XCD gets a contiguous 3-row tile band
    const int traw = blockIdx.x;
    const int tile = (traw & 7) * 72 + (traw >> 3);
    const int b = blockIdx.y;
    const int ty0 = (tile / 24) * 8, tx0 = (tile % 24) * 8;
    const int lane = t & 63;
    const int w = __builtin_amdgcn_readfirstlane(t >> 6);   // 0..3 (oc-group)
    const int l15 = lane & 15, l4 = lane >> 4;
    const int ys0 = (ty0 >> 2) - 1, xs0 = (tx0 >> 2) - 1;

    f32x4 acc[2][4];                                 // [mf: oc 16-half][nf: pixel 16-block]
#pragma unroll
    for (int m = 0; m < 2; ++m)
#pragma unroll
        for (int n = 0; n < 4; ++n) acc[m][n] = (f32x4){0.f, 0.f, 0.f, 0.f};

    // p-wise resize cells/weights (group/tap independent)
    if (t < 64) {
        int p = t;
        int y = ty0 + (p >> 3), xx = tx0 + (p & 7);
        float ysf = fminf(fmaxf((y + 0.5f) * 0.25f - 0.5f, 0.f), 47.f);
        float xsf = fminf(fmaxf((xx + 0.5f) * 0.25f - 0.5f, 0.f), 47.f);
        int ry0 = (int)ysf, rx0 = (int)xsf;
        float fy = ysf - (float)ry0, fx = xsf - (float)rx0;
        rb[p] = (ry0 - ys0) * 4 + (rx0 - xs0);
        rw[0][p] = (1.f - fy) * (1.f - fx);
        rw[1][p] = (1.f - fy) * fx;
        rw[2][p] = fy * (1.f - fx);
        rw[3][p] = fy * fx;
    }
    // zero K-pad units (cols 72..95) of both val buffers (384 units over 256 threads)
    for (int i = t; i < 384; i += 256) {
        int bb = (i >= 192) ? 1 : 0; int j = i - bb * 192;
        int row = j / 3, un = 9 + j % 3;
        *reinterpret_cast<uint4*>(&val[bb][row * 104 + un * 8]) = make_uint4(0, 0, 0, 0);
    }

    const float* a4b = a4 + (size_t)b * C4 * HWS;
    const float* flb = flow + (size_t)b * 32 * HW;
    const u16* xgb0 = xg + (size_t)b * DG_ * HW * 8;

#define STAGE(gg, bb) do {                                                          \
    const int gk = (gg);                                                            \
    for (int i = t; i < 432; i += 256) {                                            \
        int ch = i >> 4, idx = i & 15;                                              \
        int gy = min(max(ys0 + (idx >> 2), 0), 47);                                 \
        int gx = min(max(xs0 + (idx & 3), 0), 47);                                  \
        int a4ch = (ch < 18) ? (gk * 18 + ch) : (288 + gk * 9 + (ch - 18));         \
        a4t[bb][i] = a4b[(size_t)a4ch * HWS + gy * 48 + gx];                        \
    }                                                                               \
    if (t < 128) {                                                                  \
        int comp = t >> 6, p = t & 63;                                              \
        int y = ty0 + (p >> 3), xx = tx0 + (p & 7);                                 \
        flds[bb][t] = flb[(size_t)(2 * gk + 1 - comp) * HW + y * WW + xx];          \
    }                                                                               \
} while (0)

#define PH12(gg, bb) do {                                                           \
    const u16* xgb = xgb0 + (size_t)(gg) * HW * 8;                                  \
    for (int i = t; i < 576; i += 256) {                                            \
        int k = i >> 6, p = i & 63;                                                 \
        int y = ty0 + (p >> 3), xx = tx0 + (p & 7);                                 \
        int base = rb[p];                                                           \
        float r00 = rw[0][p], r01 = rw[1][p], r10 = rw[2][p], r11 = rw[3][p];       \
        const float* A = &a4t[bb][0];                                               \
        float sdy = A[(2*k)*16+base]*r00 + A[(2*k)*16+base+1]*r01                   \
                  + A[(2*k)*16+base+4]*r10 + A[(2*k)*16+base+5]*r11;                \
        float sdx = A[(2*k+1)*16+base]*r00 + A[(2*k+1)*16+base+1]*r01               \
                  + A[(2*k+1)*16+base+4]*r10 + A[(2*k+1)*16+base+5]*r11;            \
        float sm  = A[(18+k)*16+base]*r00 + A[(18+k)*16+base+1]*r01                 \
                  + A[(18+k)*16+base+4]*r10 + A[(18+k)*16+base+5]*r11;              \
        float dyv = 5.f * tanh_fast(sdy) + flds[bb][p];                             \
        float dxv = 5.f * tanh_fast(sdx) + flds[bb][64 + p];                        \
        float m = sigmoid_fast(sm);                                                 \
        float fpy = (float)(y + (k / 3) - 1) + dyv;                                 \
        float fpx = (float)(xx + (k % 3) - 1) + dxv;                                \
        float y0f = floorf(fpy), x0f = floorf(fpx);                                 \
        int gy0 = (int)y0f, gx0 = (int)x0f;                                         \
        int gy1 = gy0 + 1, gx1 = gx0 + 1;                                           \
        float wy = fpy - y0f, wx = fpx - x0f;                                       \
        bool by0 = (unsigned)gy0 < (unsigned)HH, by1 = (unsigned)gy1 < (unsigned)HH;\
        bool bx0 = (unsigned)gx0 < (unsigned)WW, bx1 = (unsigned)gx1 < (unsigned)WW;\
        int y0c = min(max(gy0, 0), HH - 1), y1c = min(max(gy1, 0), HH - 1);         \
        int x0c = min(max(gx0, 0), WW - 1), x1c = min(max(gx1, 0), WW - 1);         \
        float w00 = (by0 && bx0) ? (1.f - wy) * (1.f - wx) * m : 0.f;               \
        float w01 = (by0 && bx1) ? (1.f - wy) * wx * m : 0.f;                       \
        float w10 = (by1 && bx0) ? wy * (1.f - wx) * m : 0.f;                       \
        float w11 = (by1 && bx1) ? wy * wx * m : 0.f;                               \
        uint4 v00 = *reinterpret_cast<const uint4*>(&xgb[(size_t)(y0c * WW + x0c) * 8]); \
        uint4 v01 = *reinterpret_cast<const uint4*>(&xgb[(size_t)(y0c * WW + x1c) * 8]); \
        uint4 v10 = *reinterpret_cast<const uint4*>(&xgb[(size_t)(y1c * WW + x0c) * 8]); \
        uint4 v11 = *reinterpret_cast<const uint4*>(&xgb[(size_t)(y1c * WW + x1c) * 8]); \
        const __half2* h00 = reinterpret_cast<const __half2*>(&v00);                \
        const __half2* h01 = reinterpret_cast<const __half2*>(&v01);                \
        const __half2* h10 = reinterpret_cast<const __half2*>(&v10);                \
        const __half2* h11 = reinterpret_cast<const __half2*>(&v11);                \
        __half hw00 = __float2half_rn(w00), hw01 = __float2half_rn(w01);            \
        __half hw10 = __float2half_rn(w10), hw11 = __float2half_rn(w11);            \
        __half2 W00{hw00, hw00}, W01{hw01, hw01}, W10{hw10, hw10}, W11{hw11, hw11}; \
        union { __half2 h2[4]; uint4 u4; } uu;                                      \
        _Pragma("unroll")                                                           \
        for (int cc = 0; cc < 4; ++cc)                                              \
            uu.h2[cc] = __hfma2(h00[cc], W00, __hfma2(h01[cc], W01,                 \
                        __hfma2(h10[cc], W10, __hmul2(h11[cc], W11))));             \
        *reinterpret_cast<uint4*>(&val[bb][p * 104 + k * 8]) = uu.u4;               \
    }                                                                               \
} while (0)

    STAGE(0, 0);
    __syncthreads();

    for (int g = 0; g < DG_; ++g) {
        const int buf = g & 1;
        if (g < 15) STAGE(g + 1, buf ^ 1);
        PH12(g, buf);
        __syncthreads();
        const u16* wg = wA + (size_t)(w * 32) * 1536 + g * 96;
        __builtin_amdgcn_s_setprio(1);
#pragma unroll
        for (int kb = 0; kb < 3; ++kb) {
            f16x8 a0 = *reinterpret_cast<const f16x8*>(wg + (size_t)l15 * 1536 + kb * 32 + l4 * 8);
            f16x8 a1 = *reinterpret_cast<const f16x8*>(wg + (size_t)(16 + l15) * 1536 + kb * 32 + l4 * 8);
#pragma unroll
            for (int nf = 0; nf < 4; ++nf) {
                int row = nf * 16 + l15;
                f16x8 bfrag = *reinterpret_cast<const f16x8*>(
                    &val[buf][row * 104 + kb * 32 + l4 * 8]);
                acc[0][nf] = __builtin_amdgcn_mfma_f32_16x16x32_f16(a0, bfrag, acc[0][nf], 0, 0, 0);
                acc[1][nf] = __builtin_amdgcn_mfma_f32_16x16x32_f16(a1, bfrag, acc[1][nf], 0, 0, 0);
            }
        }
        __builtin_amdgcn_s_setprio(0);
    }
#undef STAGE
#undef PH12
    // epilogue: D col=lane&15 (pixel), row=(lane>>4)*4+reg (oc within 16)
#pragma unroll
    for (int mf = 0; mf < 2; ++mf)
#pragma unroll
        for (int nf = 0; nf < 4; ++nf) {
            int pix = nf * 16 + l15;
            int py = ty0 + (pix >> 3), px = tx0 + (pix & 7);
#pragma unroll
            for (int r = 0; r < 4; ++r) {
                int o = w * 32 + mf * 16 + l4 * 4 + r;
                out[((size_t)(b * COUT_D + o) * HH + py) * WW + px] = acc[mf][nf][r] + bias[o];
            }
        }
}

extern "C" void kernel_launch(void* const* d_in, const int* in_sizes, int n_in,
                              void* d_out, int out_size, void* d_ws, size_t ws_size,
                              hipStream_t stream) {
    const float* x    = (const float*)d_in[0];
    const float* flow = (const float*)d_in[1];
    const float* addf = (const float*)d_in[2];
    const float* w1   = (const float*)d_in[3];
    const float* b1   = (const float*)d_in[4];
    const float* w2   = (const float*)d_in[5];
    const float* b2   = (const float*)d_in[6];
    const float* w3   = (const float*)d_in[7];
    const float* b3   = (const float*)d_in[8];
    const float* w4   = (const float*)d_in[9];
    const float* b4   = (const float*)d_in[10];
    const float* wgt  = (const float*)d_in[11];
    const float* bias = (const float*)d_in[12];
    float* out = (float*)d_out;
    float* ws = (float*)d_ws;

    float* zp    = ws;                               // 256 f32
    u16*  pool_t = (u16*)(ws + 256);                 // 1,474,560 u16
    u16*  c1     = pool_t + 1474560;                 // 589,824 u16
    u16*  c2     = c1 + 589824;                      // 589,824 u16
    u16*  c3     = c1;                               // alias (c1 dead after conv2)
    float* a4    = (float*)(c2 + 589824);            // 1,990,656 f32
    u16*  wq1    = (u16*)(a4 + 1990656);             // 184,320 u16
    u16*  wq2    = wq1 + 184320;                     // 73,728
    u16*  wq3    = wq2 + 73728;                      // 73,728
    u16*  wq4    = wq3 + 73728;                      // 516,096
    u16*  wA     = wq4 + 516096;                     // 196,608 (fp16)
    u16*  xg     = wA + 196608;                      // 9,437,184 (fp16)

    fused_prep_kernel      <<<4081, 256, 0, stream>>>(w1, w2, w3, w4, wgt, zp, wq1, wq2, wq3, wq4, wA);
    fused_trans_pool_kernel<<<7488, 256, 0, stream>>>(x, flow, addf, xg, pool_t);

    conv_ks<160, 12, 23, 34, 45, true><<<dim3(144, 1, 2), 1024, 0, stream>>>(pool_t, wq1, b1, c1, zp);
    conv_ks<64,  5,  10, 14, 18, true><<<dim3(144, 1, 2), 1024, 0, stream>>>(c1, wq2, b2, c2, zp);
    conv_ks<64,  5,  10, 14, 18, true><<<dim3(144, 1, 2), 1024, 0, stream>>>(c2, wq3, b3, c3, zp);
    conv_mfma<64, 432, 448, false><<<dim3(144, 7, 2), 256, 0, stream>>>(c3, wq4, b4, a4, zp);

    deform_mfma<<<dim3(576, 2), 256, 0, stream>>>(xg, flow, a4, wA, bias, out);
}

// Round 11
// 250.078 us; speedup vs baseline: 1.1940x; 1.1940x over previous
//
#include <hip/hip_runtime.h>
#include <hip/hip_fp16.h>

#define B_ 2
#define CX 64
#define HH 192
#define WW 192
#define HW (HH*WW)
#define HS 48
#define WS 48
#define HWS (HS*WS)
#define CE 160
#define C4 432
#define DG_ 16
#define COUT_D 128

typedef short bf16x8 __attribute__((ext_vector_type(8)));
typedef _Float16 f16x8 __attribute__((ext_vector_type(8)));
typedef float f32x4 __attribute__((ext_vector_type(4)));
typedef unsigned short u16;

__device__ __forceinline__ unsigned f2bf(float f) {
    unsigned u = __float_as_uint(f);
    return (u + 0x7FFFu + ((u >> 16) & 1u)) >> 16;   // RNE
}
__device__ __forceinline__ float bf2f(u16 h) {
    return __uint_as_float(((unsigned)h) << 16);
}
__device__ __forceinline__ void split_hl(float v, u16& h, u16& l) {
    h = (u16)f2bf(v);
    l = (u16)f2bf(v - bf2f(h));
}
__device__ __forceinline__ float tanh_fast(float v) {
    float e = __expf(2.f * v);
    return 1.f - 2.f * __builtin_amdgcn_rcpf(e + 1.f);
}
__device__ __forceinline__ float sigmoid_fast(float s) {
    return __builtin_amdgcn_rcpf(1.f + __expf(-s));
}

// ---------------- fused prep: zp + wq1..wq4 + wA ----------------
__device__ __forceinline__ void prep_wq_body(const float* __restrict__ w, u16* __restrict__ wq,
                                             int i, int OC, int OCP, int CIN) {
    int ic = i % CIN; int rest = i / CIN;
    int oc = rest % OCP; rest /= OCP;
    int q = rest % 9; int kind = rest / 9;
    float v = (oc < OC) ? w[((size_t)oc * CIN + ic) * 9 + q] : 0.f;
    u16 h, l; split_hl(v, h, l);
    wq[i] = kind ? l : h;
}

__global__ void fused_prep_kernel(const float* __restrict__ w1, const float* __restrict__ w2,
                                  const float* __restrict__ w3, const float* __restrict__ w4,
                                  const float* __restrict__ wgt,
                                  float* __restrict__ zp, u16* __restrict__ wq1,
                                  u16* __restrict__ wq2, u16* __restrict__ wq3,
                                  u16* __restrict__ wq4, u16* __restrict__ wA) {
    int bid = blockIdx.x, t = threadIdx.x;
    if (bid == 0) { zp[t] = 0.f; return; }
    if (bid < 721)  { prep_wq_body(w1, wq1, (bid - 1) * 256 + t, 64, 64, 160); return; }
    if (bid < 1009) { prep_wq_body(w2, wq2, (bid - 721) * 256 + t, 64, 64, 64); return; }
    if (bid < 1297) { prep_wq_body(w3, wq3, (bid - 1009) * 256 + t, 64, 64, 64); return; }
    if (bid < 3313) { prep_wq_body(w4, wq4, (bid - 1297) * 256 + t, 432, 448, 64); return; }
    // wA fp16: [o][g*96 + tap*8 + c], taps 9..11 = 0
    int i = (bid - 3313) * 256 + t;                  // 128*1536 = 768*256
    int o = i / 1536, col = i - o * 1536;
    int g = col / 96, r = col - g * 96;
    int tap = r >> 3, c = r & 7;
    float v = (tap < 9) ? wgt[(size_t)o * 1152 + (g * 8 + c) * 9 + tap] : 0.f;
    wA[i] = __half_as_ushort(__float2half_rn(v));
}

// ---------------- fused: x/addf -> NHWC fp16 xg ; avgpool4+concat -> pool_t ----------------
__global__ void fused_trans_pool_kernel(const float* __restrict__ x, const float* __restrict__ flow,
                                        const float* __restrict__ addf,
                                        u16* __restrict__ xg, u16* __restrict__ pt) {
    int bid = blockIdx.x, t = threadIdx.x;
    if (bid < 4608) {
        int i = bid * 256 + t;                       // 2*16*36864
        int p = i % HW;
        int g = (i / HW) % DG_;
        int b = i / (HW * DG_);
        const float* xb = x    + ((size_t)(b * CX + g * 4)) * HW + p;
        const float* ab = addf + ((size_t)(b * CX + g * 4)) * HW + p;
        __half2 h[4];
        h[0].x = __float2half_rn(xb[0]);      h[0].y = __float2half_rn(xb[HW]);
        h[1].x = __float2half_rn(xb[2 * HW]); h[1].y = __float2half_rn(xb[3 * HW]);
        h[2].x = __float2half_rn(ab[0]);      h[2].y = __float2half_rn(ab[HW]);
        h[3].x = __float2half_rn(ab[2 * HW]); h[3].y = __float2half_rn(ab[3 * HW]);
        *reinterpret_cast<uint4*>(&xg[(size_t)i * 8]) = *reinterpret_cast<uint4*>(h);
    } else {
        int i = (bid - 4608) * 256 + t;              // 737280
        int xs = i % WS, ys = (i / WS) % HS, c = (i / HWS) % CE, b = i / (HWS * CE);
        const float* src;
        if (c < 64)      src = x    + (size_t)(b * 64 + c) * HW;
        else if (c < 96) src = flow + (size_t)(b * 32 + (c - 64)) * HW;
        else             src = addf + (size_t)(b * 64 + (c - 96)) * HW;
        const float4* s4 = reinterpret_cast<const float4*>(src + (ys * 4) * WW + xs * 4);
        float sum = 0.f;
#pragma unroll
        for (int r = 0; r < 4; ++r) {
            float4 v = s4[r * (WW / 4)];
            sum += v.x + v.y + v.z + v.w;
        }
        float v = sum * (1.f / 16.f);
        u16 h, l; split_hl(v, h, l);
        size_t base = ((size_t)(b * HWS + ys * WS + xs) * 2) * CE + c;
        pt[base] = h; pt[base + CE] = l;
    }
}

// ---------------- 4-way K-split MFMA 3x3 conv (64 oc), LDS-staged input tile ----------------
// block = 1024 threads (16 waves: 4 ocgrp x 4 ksplit), tile = 4x4 px, halo 6x6 staged in LDS
template<int CIN, int U0, int U1, int U2, int UT, bool LRELU>
__global__ __launch_bounds__(1024) void conv_ks(const u16* __restrict__ in_t,
                                                const u16* __restrict__ wq,
                                                const float* __restrict__ bias,
                                                u16* __restrict__ out_t) {
    constexpr int CP = CIN + 4;                      // padded channel stride (bank de-alias)
    __shared__ u16 tile_in[36 * 2 * CP];             // [spx 6x6][kind hi/lo][c]
    __shared__ float red[3 * 4 * 256];               // [ks-1][ocgrp][r*64+lane]
    const int t = threadIdx.x;
    const int w = t >> 6;
    const int ocgrp = w & 3, ks = w >> 2;
    const int lane = t & 63;
    const int l15 = t & 15, l4 = (t >> 4) & 3;
    const int tile = blockIdx.x;
    const int ty0 = (tile / 12) * 4, tx0 = (tile % 12) * 4;
    const int b = blockIdx.z;
    const int ocb = ocgrp * 16;
    const int py = ty0 + (l15 >> 2), pxx = tx0 + (l15 & 3);
    const u16* inb = in_t + (size_t)b * (HWS * 2 * CIN);

    // stage 6x6 halo (zero-padded), coalesced uint4
    for (int i = t; i < 36 * 2 * (CIN / 8); i += 1024) {
        int c8 = i % (CIN / 8); int rest = i / (CIN / 8);
        int kind = rest & 1; int spx = rest >> 1;
        int gy = ty0 - 1 + spx / 6, gx = tx0 - 1 + spx % 6;
        uint4 v = make_uint4(0, 0, 0, 0);
        if ((unsigned)gy < 48u && (unsigned)gx < 48u)
            v = *reinterpret_cast<const uint4*>(&inb[((size_t)(gy * 48 + gx) * 2 + kind) * CIN + c8 * 8]);
        *reinterpret_cast<uint4*>(&tile_in[(spx * 2 + kind) * CP + c8 * 8]) = v;
    }
    __syncthreads();

    f32x4 ahh = {0,0,0,0}, ahl = {0,0,0,0}, alh = {0,0,0,0};
    constexpr int KB = CIN / 32;
    const int lpy = l15 >> 2, lpx = l15 & 3;

#define CONV_BODY(US, UE)                                                             \
    _Pragma("unroll")                                                                 \
    for (int u = (US); u < (UE); ++u) {                                               \
        const int q = u / KB, kb = u % KB;                                            \
        const int spx = (lpy + q / 3) * 6 + (lpx + q % 3);                            \
        const u16* bh = &tile_in[(spx * 2 + 0) * CP + kb * 32 + l4 * 8];              \
        const u16* bl = &tile_in[(spx * 2 + 1) * CP + kb * 32 + l4 * 8];              \
        const u16* wh = wq + ((size_t)q * 64 + ocb + l15) * CIN + l4 * 8 + kb * 32;   \
        const u16* wl = wh + (size_t)9 * 64 * CIN;                                    \
        bf16x8 Ah = *reinterpret_cast<const bf16x8*>(wh);                             \
        bf16x8 Al = *reinterpret_cast<const bf16x8*>(wl);                             \
        bf16x8 Bh = *reinterpret_cast<const bf16x8*>(bh);                             \
        bf16x8 Bl = *reinterpret_cast<const bf16x8*>(bl);                             \
        ahh = __builtin_amdgcn_mfma_f32_16x16x32_bf16(Ah, Bh, ahh, 0, 0, 0);          \
        ahl = __builtin_amdgcn_mfma_f32_16x16x32_bf16(Ah, Bl, ahl, 0, 0, 0);          \
        alh = __builtin_amdgcn_mfma_f32_16x16x32_bf16(Al, Bh, alh, 0, 0, 0);          \
    }
    if (ks == 0)      { CONV_BODY(0,  U0) }
    else if (ks == 1) { CONV_BODY(U0, U1) }
    else if (ks == 2) { CONV_BODY(U1, U2) }
    else              { CONV_BODY(U2, UT) }
#undef CONV_BODY

    float vsum[4];
#pragma unroll
    for (int r = 0; r < 4; ++r) vsum[r] = ahh[r] + ahl[r] + alh[r];
    if (ks) {
#pragma unroll
        for (int r = 0; r < 4; ++r)
            red[((ks - 1) * 4 + ocgrp) * 256 + r * 64 + lane] = vsum[r];
    }
    __syncthreads();
    if (!ks) {
#pragma unroll
        for (int r = 0; r < 4; ++r) {
#pragma unroll
            for (int j = 0; j < 3; ++j)
                vsum[r] += red[(j * 4 + ocgrp) * 256 + r * 64 + lane];
            int oc = ocb + l4 * 4 + r;
            float v = vsum[r] + bias[oc];
            if (LRELU) v = (v >= 0.f) ? v : 0.2f * v;
            u16 h, l; split_hl(v, h, l);
            size_t base = ((size_t)(b * HWS + py * 48 + pxx) * 2) * 64 + oc;
            out_t[base] = h; out_t[base + 64] = l;
        }
    }
}

// ---------------- MFMA 3x3 conv (conv4: 432 oc, f32 out), 4 waves ----------------
template<int CIN, int OC, int OCP, bool LRELU>
__global__ __launch_bounds__(256) void conv_mfma(const u16* __restrict__ in_t,
                                                 const u16* __restrict__ wq,
                                                 const float* __restrict__ bias,
                                                 float* __restrict__ out_f,
                                                 const float* __restrict__ zp) {
    const int t = threadIdx.x;
    const int wv = __builtin_amdgcn_readfirstlane(t >> 6);
    const int l15 = t & 15, l4 = (t >> 4) & 3;
    const int tile = blockIdx.x;
    const int ty0 = (tile / 12) * 4, tx0 = (tile % 12) * 4;
    const int ocb = blockIdx.y * 64 + wv * 16;
    const int b = blockIdx.z;
    const int py = ty0 + (l15 >> 2), pxx = tx0 + (l15 & 3);
    f32x4 ahh = {0,0,0,0}, ahl = {0,0,0,0}, alh = {0,0,0,0};
    const u16* inb = in_t + (size_t)b * (HWS * 2 * CIN);
    const u16* zp16 = (const u16*)zp;
#pragma unroll
    for (int q = 0; q < 9; ++q) {
        int sy = py + q / 3 - 1, sx = pxx + q % 3 - 1;
        bool valid = ((unsigned)sy < 48u) && ((unsigned)sx < 48u);
        const u16* bh = valid ? inb + ((size_t)(sy * 48 + sx) * 2) * CIN : zp16;
        const u16* bl = valid ? inb + ((size_t)(sy * 48 + sx) * 2 + 1) * CIN : zp16;
        const u16* wh = wq + ((size_t)q * OCP + ocb + l15) * CIN + l4 * 8;
        const u16* wl = wq + ((size_t)(9 + q) * OCP + ocb + l15) * CIN + l4 * 8;
#pragma unroll
        for (int kb = 0; kb < CIN / 32; ++kb) {
            bf16x8 Ah = *reinterpret_cast<const bf16x8*>(wh + kb * 32);
            bf16x8 Al = *reinterpret_cast<const bf16x8*>(wl + kb * 32);
            bf16x8 Bh = *reinterpret_cast<const bf16x8*>(bh + kb * 32 + l4 * 8);
            bf16x8 Bl = *reinterpret_cast<const bf16x8*>(bl + kb * 32 + l4 * 8);
            ahh = __builtin_amdgcn_mfma_f32_16x16x32_bf16(Ah, Bh, ahh, 0, 0, 0);
            ahl = __builtin_amdgcn_mfma_f32_16x16x32_bf16(Ah, Bl, ahl, 0, 0, 0);
            alh = __builtin_amdgcn_mfma_f32_16x16x32_bf16(Al, Bh, alh, 0, 0, 0);
        }
    }
#pragma unroll
    for (int r = 0; r < 4; ++r) {
        int oc = ocb + l4 * 4 + r;
        float v = ahh[r] + ahl[r] + alh[r] + ((oc < OC) ? bias[oc] : 0.f);
        if (LRELU) v = (v >= 0.f) ? v : 0.2f * v;
        if (oc < OC) out_f[((size_t)(b * OC + oc)) * HWS + py * 48 + pxx] = v;
    }
}

// ---------------- deform v9 (R9 verbatim — passing): R5 skeleton + setprio + XCD swizzle ----------------
__global__ __launch_bounds__(512) void deform_mfma(
    const u16* __restrict__ xg, const float* __restrict__ flow,
    const float* __restrict__ a4, const u16* __restrict__ wA,
    const float* __restrict__ bias, float* __restrict__ out)
{
    __shared__ u16 val[2][64 * 104];                 // fp16 [pixel][ck pad 96->104]
    __shared__ float a4t[2][27 * 16];
    __shared__ float flds[2][128];
    __shared__ float rw[4][64];
    __shared__ int rb[64];
    const int t = threadIdx.x;
    // XCD-aware swizzle: 576 = 8 * 72 -> each XCD gets a contiguous 3-row tile band
    const int traw = blockIdx.x;
    const int tile = (traw & 7) * 72 + (traw >> 3);
    const int b = blockIdx.y;
    const int ty0 = (tile / 24) * 8, tx0 = (tile % 24) * 8;
    const int lane = t & 63;
    const int og = __builtin_amdgcn_readfirstlane(t >> 6);
    const int l15 = lane & 15, l4 = lane >> 4;
    const int ys0 = (ty0 >> 2) - 1, xs0 = (tx0 >> 2) - 1;

    f32x4 acc[4];
#pragma unroll
    for (int n = 0; n < 4; ++n) acc[n] = (f32x4){0.f, 0.f, 0.f, 0.f};

    // p-wise resize cells/weights (group/tap independent)
    if (t < 64) {
        int p = t;
        int y = ty0 + (p >> 3), xx = tx0 + (p & 7);
        float ysf = fminf(fmaxf((y + 0.5f) * 0.25f - 0.5f, 0.f), 47.f);
        float xsf = fminf(fmaxf((xx + 0.5f) * 0.25f - 0.5f, 0.f), 47.f);
        int ry0 = (int)ysf, rx0 = (int)xsf;
        float fy = ysf - (float)ry0, fx = xsf - (float)rx0;
        rb[p] = (ry0 - ys0) * 4 + (rx0 - xs0);
        rw[0][p] = (1.f - fy) * (1.f - fx);
        rw[1][p] = (1.f - fy) * fx;
        rw[2][p] = fy * (1.f - fx);
        rw[3][p] = fy * fx;
    }
    // zero K-pad units (cols 72..95) of both val buffers
    if (t < 384) {
        int bb = (t >= 192) ? 1 : 0; int j = t - bb * 192;
        int row = j / 3, un = 9 + j % 3;
        *reinterpret_cast<uint4*>(&val[bb][row * 104 + un * 8]) = make_uint4(0, 0, 0, 0);
    }

    const float* a4b = a4 + (size_t)b * C4 * HWS;
    const float* flb = flow + (size_t)b * 32 * HW;
    const u16* xgb0 = xg + (size_t)b * DG_ * HW * 8;

#define STAGE(gg, bb) do {                                                          \
    const int gk = (gg);                                                            \
    if (t < 432) {                                                                  \
        int ch = t >> 4, idx = t & 15;                                              \
        int gy = min(max(ys0 + (idx >> 2), 0), 47);                                 \
        int gx = min(max(xs0 + (idx & 3), 0), 47);                                  \
        int a4ch = (ch < 18) ? (gk * 18 + ch) : (288 + gk * 9 + (ch - 18));         \
        a4t[bb][t] = a4b[(size_t)a4ch * HWS + gy * 48 + gx];                        \
    }                                                                               \
    if (t < 128) {                                                                  \
        int comp = t >> 6, p = t & 63;                                              \
        int y = ty0 + (p >> 3), xx = tx0 + (p & 7);                                 \
        flds[bb][t] = flb[(size_t)(2 * gk + 1 - comp) * HW + y * WW + xx];          \
    }                                                                               \
} while (0)

#define PH12(gg, bb) do {                                                           \
    const u16* xgb = xgb0 + (size_t)(gg) * HW * 8;                                  \
    for (int i = t; i < 576; i += 512) {                                            \
        int k = i >> 6, p = i & 63;                                                 \
        int y = ty0 + (p >> 3), xx = tx0 + (p & 7);                                 \
        int base = rb[p];                                                           \
        float r00 = rw[0][p], r01 = rw[1][p], r10 = rw[2][p], r11 = rw[3][p];       \
        const float* A = &a4t[bb][0];                                               \
        float sdy = A[(2*k)*16+base]*r00 + A[(2*k)*16+base+1]*r01                   \
                  + A[(2*k)*16+base+4]*r10 + A[(2*k)*16+base+5]*r11;                \
        float sdx = A[(2*k+1)*16+base]*r00 + A[(2*k+1)*16+base+1]*r01               \
                  + A[(2*k+1)*16+base+4]*r10 + A[(2*k+1)*16+base+5]*r11;            \
        float sm  = A[(18+k)*16+base]*r00 + A[(18+k)*16+base+1]*r01                 \
                  + A[(18+k)*16+base+4]*r10 + A[(18+k)*16+base+5]*r11;              \
        float dyv = 5.f * tanh_fast(sdy) + flds[bb][p];                             \
        float dxv = 5.f * tanh_fast(sdx) + flds[bb][64 + p];                        \
        float m = sigmoid_fast(sm);                                                 \
        float fpy = (float)(y + (k / 3) - 1) + dyv;                                 \
        float fpx = (float)(xx + (k % 3) - 1) + dxv;                                \
        float y0f = floorf(fpy), x0f = floorf(fpx);                                 \
        int gy0 = (int)y0f, gx0 = (int)x0f;                                         \
        int gy1 = gy0 + 1, gx1 = gx0 + 1;                                           \
        float wy = fpy - y0f, wx = fpx - x0f;                                       \
        bool by0 = (unsigned)gy0 < (unsigned)HH, by1 = (unsigned)gy1 < (unsigned)HH;\
        bool bx0 = (unsigned)gx0 < (unsigned)WW, bx1 = (unsigned)gx1 < (unsigned)WW;\
        int y0c = min(max(gy0, 0), HH - 1), y1c = min(max(gy1, 0), HH - 1);         \
        int x0c = min(max(gx0, 0), WW - 1), x1c = min(max(gx1, 0), WW - 1);         \
        float w00 = (by0 && bx0) ? (1.f - wy) * (1.f - wx) * m : 0.f;               \
        float w01 = (by0 && bx1) ? (1.f - wy) * wx * m : 0.f;                       \
        float w10 = (by1 && bx0) ? wy * (1.f - wx) * m : 0.f;                       \
        float w11 = (by1 && bx1) ? wy * wx * m : 0.f;                               \
        uint4 v00 = *reinterpret_cast<const uint4*>(&xgb[(size_t)(y0c * WW + x0c) * 8]); \
        uint4 v01 = *reinterpret_cast<const uint4*>(&xgb[(size_t)(y0c * WW + x1c) * 8]); \
        uint4 v10 = *reinterpret_cast<const uint4*>(&xgb[(size_t)(y1c * WW + x0c) * 8]); \
        uint4 v11 = *reinterpret_cast<const uint4*>(&xgb[(size_t)(y1c * WW + x1c) * 8]); \
        const __half2* h00 = reinterpret_cast<const __half2*>(&v00);                \
        const __half2* h01 = reinterpret_cast<const __half2*>(&v01);                \
        const __half2* h10 = reinterpret_cast<const __half2*>(&v10);                \
        const __half2* h11 = reinterpret_cast<const __half2*>(&v11);                \
        __half hw00 = __float2half_rn(w00), hw01 = __float2half_rn(w01);            \
        __half hw10 = __float2half_rn(w10), hw11 = __float2half_rn(w11);            \
        __half2 W00{hw00, hw00}, W01{hw01, hw01}, W10{hw10, hw10}, W11{hw11, hw11}; \
        union { __half2 h2[4]; uint4 u4; } uu;                                      \
        _Pragma("unroll")                                                           \
        for (int cc = 0; cc < 4; ++cc)                                              \
            uu.h2[cc] = __hfma2(h00[cc], W00, __hfma2(h01[cc], W01,                 \
                        __hfma2(h10[cc], W10, __hmul2(h11[cc], W11))));             \
        *reinterpret_cast<uint4*>(&val[bb][p * 104 + k * 8]) = uu.u4;               \
    }                                                                               \
} while (0)

    STAGE(0, 0);
    __syncthreads();

    for (int g = 0; g < DG_; ++g) {
        const int buf = g & 1;
        if (g < 15) STAGE(g + 1, buf ^ 1);
        PH12(g, buf);
        __syncthreads();
        const u16* wg = wA + (size_t)(og * 16) * 1536 + g * 96;
        __builtin_amdgcn_s_setprio(1);
#pragma unroll
        for (int kb = 0; kb < 3; ++kb) {
            f16x8 a = *reinterpret_cast<const f16x8*>(wg + (size_t)l15 * 1536 + kb * 32 + l4 * 8);
#pragma unroll
            for (int nf = 0; nf < 4; ++nf) {
                int row = nf * 16 + l15;
                f16x8 bfrag = *reinterpret_cast<const f16x8*>(
                    &val[buf][row * 104 + kb * 32 + l4 * 8]);
                acc[nf] = __builtin_amdgcn_mfma_f32_16x16x32_f16(a, bfrag, acc[nf], 0, 0, 0);
            }
        }
        __builtin_amdgcn_s_setprio(0);
    }
#undef STAGE
#undef PH12
    // epilogue: D col=lane&15 (pixel), row=(lane>>4)*4+reg (oc within 16)
#pragma unroll
    for (int nf = 0; nf < 4; ++nf) {
        int pix = nf * 16 + l15;
        int py = ty0 + (pix >> 3), px = tx0 + (pix & 7);
#pragma unroll
        for (int r = 0; r < 4; ++r) {
            int o = og * 16 + l4 * 4 + r;
            out[((size_t)(b * COUT_D + o) * HH + py) * WW + px] = acc[nf][r] + bias[o];
        }
    }
}

extern "C" void kernel_launch(void* const* d_in, const int* in_sizes, int n_in,
                              void* d_out, int out_size, void* d_ws, size_t ws_size,
                              hipStream_t stream) {
    const float* x    = (const float*)d_in[0];
    const float* flow = (const float*)d_in[1];
    const float* addf = (const float*)d_in[2];
    const float* w1   = (const float*)d_in[3];
    const float* b1   = (const float*)d_in[4];
    const float* w2   = (const float*)d_in[5];
    const float* b2   = (const float*)d_in[6];
    const float* w3   = (const float*)d_in[7];
    const float* b3   = (const float*)d_in[8];
    const float* w4   = (const float*)d_in[9];
    const float* b4   = (const float*)d_in[10];
    const float* wgt  = (const float*)d_in[11];
    const float* bias = (const float*)d_in[12];
    float* out = (float*)d_out;
    float* ws = (float*)d_ws;

    float* zp    = ws;                               // 256 f32
    u16*  pool_t = (u16*)(ws + 256);                 // 1,474,560 u16
    u16*  c1     = pool_t + 1474560;                 // 589,824 u16
    u16*  c2     = c1 + 589824;                      // 589,824 u16
    u16*  c3     = c1;                               // alias (c1 dead after conv2)
    float* a4    = (float*)(c2 + 589824);            // 1,990,656 f32
    u16*  wq1    = (u16*)(a4 + 1990656);             // 184,320 u16
    u16*  wq2    = wq1 + 184320;                     // 73,728
    u16*  wq3    = wq2 + 73728;                      // 73,728
    u16*  wq4    = wq3 + 73728;                      // 516,096
    u16*  wA     = wq4 + 516096;                     // 196,608 (fp16)
    u16*  xg     = wA + 196608;                      // 9,437,184 (fp16)

    fused_prep_kernel      <<<4081, 256, 0, stream>>>(w1, w2, w3, w4, wgt, zp, wq1, wq2, wq3, wq4, wA);
    fused_trans_pool_kernel<<<7488, 256, 0, stream>>>(x, flow, addf, xg, pool_t);

    conv_ks<160, 12, 23, 34, 45, true><<<dim3(144, 1, 2), 1024, 0, stream>>>(pool_t, wq1, b1, c1);
    conv_ks<64,  5,  10, 14, 18, true><<<dim3(144, 1, 2), 1024, 0, stream>>>(c1, wq2, b2, c2);
    conv_ks<64,  5,  10, 14, 18, true><<<dim3(144, 1, 2), 1024, 0, stream>>>(c2, wq3, b3, c3);
    conv_mfma<64, 432, 448, false><<<dim3(144, 7, 2), 256, 0, stream>>>(c3, wq4, b4, a4, zp);

    deform_mfma<<<dim3(576, 2), 512, 0, stream>>>(xg, flow, a4, wA, bias, out);
}

// Round 12
// 238.411 us; speedup vs baseline: 1.2524x; 1.0489x over previous
//
#include <hip/hip_runtime.h>
#include <hip/hip_fp16.h>

#define B_ 2
#define CX 64
#define HH 192
#define WW 192
#define HW (HH*WW)
#define HS 48
#define WS 48
#define HWS (HS*WS)
#define CE 160
#define C4 432
#define DG_ 16
#define COUT_D 128

typedef short bf16x8 __attribute__((ext_vector_type(8)));
typedef _Float16 f16x8 __attribute__((ext_vector_type(8)));
typedef float f32x4 __attribute__((ext_vector_type(4)));
typedef unsigned short u16;

__device__ __forceinline__ unsigned f2bf(float f) {
    unsigned u = __float_as_uint(f);
    return (u + 0x7FFFu + ((u >> 16) & 1u)) >> 16;   // RNE
}
__device__ __forceinline__ float bf2f(u16 h) {
    return __uint_as_float(((unsigned)h) << 16);
}
__device__ __forceinline__ void split_hl(float v, u16& h, u16& l) {
    h = (u16)f2bf(v);
    l = (u16)f2bf(v - bf2f(h));
}
__device__ __forceinline__ float tanh_fast(float v) {
    float e = __expf(2.f * v);
    return 1.f - 2.f * __builtin_amdgcn_rcpf(e + 1.f);
}
__device__ __forceinline__ float sigmoid_fast(float s) {
    return __builtin_amdgcn_rcpf(1.f + __expf(-s));
}

// ---------------- fused prep: zp + wq1..wq4 + wA ----------------
__device__ __forceinline__ void prep_wq_body(const float* __restrict__ w, u16* __restrict__ wq,
                                             int i, int OC, int OCP, int CIN) {
    int ic = i % CIN; int rest = i / CIN;
    int oc = rest % OCP; rest /= OCP;
    int q = rest % 9; int kind = rest / 9;
    float v = (oc < OC) ? w[((size_t)oc * CIN + ic) * 9 + q] : 0.f;
    u16 h, l; split_hl(v, h, l);
    wq[i] = kind ? l : h;
}

__global__ void fused_prep_kernel(const float* __restrict__ w1, const float* __restrict__ w2,
                                  const float* __restrict__ w3, const float* __restrict__ w4,
                                  const float* __restrict__ wgt,
                                  float* __restrict__ zp, u16* __restrict__ wq1,
                                  u16* __restrict__ wq2, u16* __restrict__ wq3,
                                  u16* __restrict__ wq4, u16* __restrict__ wA) {
    int bid = blockIdx.x, t = threadIdx.x;
    if (bid == 0) { zp[t] = 0.f; return; }
    if (bid < 721)  { prep_wq_body(w1, wq1, (bid - 1) * 256 + t, 64, 64, 160); return; }
    if (bid < 1009) { prep_wq_body(w2, wq2, (bid - 721) * 256 + t, 64, 64, 64); return; }
    if (bid < 1297) { prep_wq_body(w3, wq3, (bid - 1009) * 256 + t, 64, 64, 64); return; }
    if (bid < 3313) { prep_wq_body(w4, wq4, (bid - 1297) * 256 + t, 432, 448, 64); return; }
    // wA fp16: [o][g*96 + tap*8 + c], taps 9..11 = 0
    int i = (bid - 3313) * 256 + t;                  // 128*1536 = 768*256
    int o = i / 1536, col = i - o * 1536;
    int g = col / 96, r = col - g * 96;
    int tap = r >> 3, c = r & 7;
    float v = (tap < 9) ? wgt[(size_t)o * 1152 + (g * 8 + c) * 9 + tap] : 0.f;
    wA[i] = __half_as_ushort(__float2half_rn(v));
}

// ---------------- fused: x/addf -> NHWC fp16 xg ; avgpool4+concat -> pool_t ----------------
__global__ void fused_trans_pool_kernel(const float* __restrict__ x, const float* __restrict__ flow,
                                        const float* __restrict__ addf,
                                        u16* __restrict__ xg, u16* __restrict__ pt) {
    int bid = blockIdx.x, t = threadIdx.x;
    if (bid < 4608) {
        int i = bid * 256 + t;                       // 2*16*36864
        int p = i % HW;
        int g = (i / HW) % DG_;
        int b = i / (HW * DG_);
        const float* xb = x    + ((size_t)(b * CX + g * 4)) * HW + p;
        const float* ab = addf + ((size_t)(b * CX + g * 4)) * HW + p;
        __half2 h[4];
        h[0].x = __float2half_rn(xb[0]);      h[0].y = __float2half_rn(xb[HW]);
        h[1].x = __float2half_rn(xb[2 * HW]); h[1].y = __float2half_rn(xb[3 * HW]);
        h[2].x = __float2half_rn(ab[0]);      h[2].y = __float2half_rn(ab[HW]);
        h[3].x = __float2half_rn(ab[2 * HW]); h[3].y = __float2half_rn(ab[3 * HW]);
        *reinterpret_cast<uint4*>(&xg[(size_t)i * 8]) = *reinterpret_cast<uint4*>(h);
    } else {
        int i = (bid - 4608) * 256 + t;              // 737280
        int xs = i % WS, ys = (i / WS) % HS, c = (i / HWS) % CE, b = i / (HWS * CE);
        const float* src;
        if (c < 64)      src = x    + (size_t)(b * 64 + c) * HW;
        else if (c < 96) src = flow + (size_t)(b * 32 + (c - 64)) * HW;
        else             src = addf + (size_t)(b * 64 + (c - 96)) * HW;
        const float4* s4 = reinterpret_cast<const float4*>(src + (ys * 4) * WW + xs * 4);
        float sum = 0.f;
#pragma unroll
        for (int r = 0; r < 4; ++r) {
            float4 v = s4[r * (WW / 4)];
            sum += v.x + v.y + v.z + v.w;
        }
        float v = sum * (1.f / 16.f);
        u16 h, l; split_hl(v, h, l);
        size_t base = ((size_t)(b * HWS + ys * WS + xs) * 2) * CE + c;
        pt[base] = h; pt[base + CE] = l;
    }
}

// ---------------- 4-way K-split MFMA 3x3 conv (64 oc), LDS-staged input tile ----------------
template<int CIN, int U0, int U1, int U2, int UT, bool LRELU>
__global__ __launch_bounds__(1024) void conv_ks(const u16* __restrict__ in_t,
                                                const u16* __restrict__ wq,
                                                const float* __restrict__ bias,
                                                u16* __restrict__ out_t) {
    constexpr int CP = CIN + 4;                      // padded channel stride (bank de-alias)
    __shared__ u16 tile_in[36 * 2 * CP];             // [spx 6x6][kind hi/lo][c]
    __shared__ float red[3 * 4 * 256];               // [ks-1][ocgrp][r*64+lane]
    const int t = threadIdx.x;
    const int w = t >> 6;
    const int ocgrp = w & 3, ks = w >> 2;
    const int lane = t & 63;
    const int l15 = t & 15, l4 = (t >> 4) & 3;
    const int tile = blockIdx.x;
    const int ty0 = (tile / 12) * 4, tx0 = (tile % 12) * 4;
    const int b = blockIdx.z;
    const int ocb = ocgrp * 16;
    const int py = ty0 + (l15 >> 2), pxx = tx0 + (l15 & 3);
    const u16* inb = in_t + (size_t)b * (HWS * 2 * CIN);

    // stage 6x6 halo (zero-padded), coalesced uint4
    for (int i = t; i < 36 * 2 * (CIN / 8); i += 1024) {
        int c8 = i % (CIN / 8); int rest = i / (CIN / 8);
        int kind = rest & 1; int spx = rest >> 1;
        int gy = ty0 - 1 + spx / 6, gx = tx0 - 1 + spx % 6;
        uint4 v = make_uint4(0, 0, 0, 0);
        if ((unsigned)gy < 48u && (unsigned)gx < 48u)
            v = *reinterpret_cast<const uint4*>(&inb[((size_t)(gy * 48 + gx) * 2 + kind) * CIN + c8 * 8]);
        *reinterpret_cast<uint4*>(&tile_in[(spx * 2 + kind) * CP + c8 * 8]) = v;
    }
    __syncthreads();

    f32x4 ahh = {0,0,0,0}, ahl = {0,0,0,0}, alh = {0,0,0,0};
    constexpr int KB = CIN / 32;
    const int lpy = l15 >> 2, lpx = l15 & 3;

#define CONV_BODY(US, UE)                                                             \
    _Pragma("unroll")                                                                 \
    for (int u = (US); u < (UE); ++u) {                                               \
        const int q = u / KB, kb = u % KB;                                            \
        const int spx = (lpy + q / 3) * 6 + (lpx + q % 3);                            \
        const u16* bh = &tile_in[(spx * 2 + 0) * CP + kb * 32 + l4 * 8];              \
        const u16* bl = &tile_in[(spx * 2 + 1) * CP + kb * 32 + l4 * 8];              \
        const u16* wh = wq + ((size_t)q * 64 + ocb + l15) * CIN + l4 * 8 + kb * 32;   \
        const u16* wl = wh + (size_t)9 * 64 * CIN;                                    \
        bf16x8 Ah = *reinterpret_cast<const bf16x8*>(wh);                             \
        bf16x8 Al = *reinterpret_cast<const bf16x8*>(wl);                             \
        bf16x8 Bh = *reinterpret_cast<const bf16x8*>(bh);                             \
        bf16x8 Bl = *reinterpret_cast<const bf16x8*>(bl);                             \
        ahh = __builtin_amdgcn_mfma_f32_16x16x32_bf16(Ah, Bh, ahh, 0, 0, 0);          \
        ahl = __builtin_amdgcn_mfma_f32_16x16x32_bf16(Ah, Bl, ahl, 0, 0, 0);          \
        alh = __builtin_amdgcn_mfma_f32_16x16x32_bf16(Al, Bh, alh, 0, 0, 0);          \
    }
    if (ks == 0)      { CONV_BODY(0,  U0) }
    else if (ks == 1) { CONV_BODY(U0, U1) }
    else if (ks == 2) { CONV_BODY(U1, U2) }
    else              { CONV_BODY(U2, UT) }
#undef CONV_BODY

    float vsum[4];
#pragma unroll
    for (int r = 0; r < 4; ++r) vsum[r] = ahh[r] + ahl[r] + alh[r];
    if (ks) {
#pragma unroll
        for (int r = 0; r < 4; ++r)
            red[((ks - 1) * 4 + ocgrp) * 256 + r * 64 + lane] = vsum[r];
    }
    __syncthreads();
    if (!ks) {
#pragma unroll
        for (int r = 0; r < 4; ++r) {
#pragma unroll
            for (int j = 0; j < 3; ++j)
                vsum[r] += red[(j * 4 + ocgrp) * 256 + r * 64 + lane];
            int oc = ocb + l4 * 4 + r;
            float v = vsum[r] + bias[oc];
            if (LRELU) v = (v >= 0.f) ? v : 0.2f * v;
            u16 h, l; split_hl(v, h, l);
            size_t base = ((size_t)(b * HWS + py * 48 + pxx) * 2) * 64 + oc;
            out_t[base] = h; out_t[base + 64] = l;
        }
    }
}

// ---------------- MFMA 3x3 conv (conv4: 432 oc, f32 out), 4 waves, LDS-staged tile ----------------
template<int CIN, int OC, int OCP, bool LRELU>
__global__ __launch_bounds__(256) void conv_mfma(const u16* __restrict__ in_t,
                                                 const u16* __restrict__ wq,
                                                 const float* __restrict__ bias,
                                                 float* __restrict__ out_f) {
    constexpr int CP = CIN + 4;
    __shared__ u16 tile_in[36 * 2 * CP];             // 9.8 KB for CIN=64
    const int t = threadIdx.x;
    const int wv = __builtin_amdgcn_readfirstlane(t >> 6);
    const int l15 = t & 15, l4 = (t >> 4) & 3;
    const int tile = blockIdx.x;
    const int ty0 = (tile / 12) * 4, tx0 = (tile % 12) * 4;
    const int ocb = blockIdx.y * 64 + wv * 16;
    const int b = blockIdx.z;
    const int py = ty0 + (l15 >> 2), pxx = tx0 + (l15 & 3);
    const u16* inb = in_t + (size_t)b * (HWS * 2 * CIN);

    for (int i = t; i < 36 * 2 * (CIN / 8); i += 256) {
        int c8 = i % (CIN / 8); int rest = i / (CIN / 8);
        int kind = rest & 1; int spx = rest >> 1;
        int gy = ty0 - 1 + spx / 6, gx = tx0 - 1 + spx % 6;
        uint4 v = make_uint4(0, 0, 0, 0);
        if ((unsigned)gy < 48u && (unsigned)gx < 48u)
            v = *reinterpret_cast<const uint4*>(&inb[((size_t)(gy * 48 + gx) * 2 + kind) * CIN + c8 * 8]);
        *reinterpret_cast<uint4*>(&tile_in[(spx * 2 + kind) * CP + c8 * 8]) = v;
    }
    __syncthreads();

    f32x4 ahh = {0,0,0,0}, ahl = {0,0,0,0}, alh = {0,0,0,0};
    const int lpy = l15 >> 2, lpx = l15 & 3;
#pragma unroll
    for (int q = 0; q < 9; ++q) {
        const int spx = (lpy + q / 3) * 6 + (lpx + q % 3);
        const u16* bh = &tile_in[(spx * 2 + 0) * CP];
        const u16* bl = &tile_in[(spx * 2 + 1) * CP];
        const u16* wh = wq + ((size_t)q * OCP + ocb + l15) * CIN + l4 * 8;
        const u16* wl = wq + ((size_t)(9 + q) * OCP + ocb + l15) * CIN + l4 * 8;
#pragma unroll
        for (int kb = 0; kb < CIN / 32; ++kb) {
            bf16x8 Ah = *reinterpret_cast<const bf16x8*>(wh + kb * 32);
            bf16x8 Al = *reinterpret_cast<const bf16x8*>(wl + kb * 32);
            bf16x8 Bh = *reinterpret_cast<const bf16x8*>(bh + kb * 32 + l4 * 8);
            bf16x8 Bl = *reinterpret_cast<const bf16x8*>(bl + kb * 32 + l4 * 8);
            ahh = __builtin_amdgcn_mfma_f32_16x16x32_bf16(Ah, Bh, ahh, 0, 0, 0);
            ahl = __builtin_amdgcn_mfma_f32_16x16x32_bf16(Ah, Bl, ahl, 0, 0, 0);
            alh = __builtin_amdgcn_mfma_f32_16x16x32_bf16(Al, Bh, alh, 0, 0, 0);
        }
    }
#pragma unroll
    for (int r = 0; r < 4; ++r) {
        int oc = ocb + l4 * 4 + r;
        float v = ahh[r] + ahl[r] + alh[r] + ((oc < OC) ? bias[oc] : 0.f);
        if (LRELU) v = (v >= 0.f) ? v : 0.2f * v;
        if (oc < OC) out_f[((size_t)(b * OC + oc)) * HWS + py * 48 + pxx] = v;
    }
}

// ---------------- deform v11: R9 skeleton, pair-granular (8 barriers), 4 buffers indexed g&3 ----------------
__global__ __launch_bounds__(512) void deform_mfma(
    const u16* __restrict__ xg, const float* __restrict__ flow,
    const float* __restrict__ a4, const u16* __restrict__ wA,
    const float* __restrict__ bias, float* __restrict__ out)
{
    __shared__ u16 val[4][64 * 104];                 // fp16 [pixel][ck pad 96->104]
    __shared__ float a4t[4][27 * 16];
    __shared__ float flds[4][128];
    __shared__ float rw[4][64];
    __shared__ int rb[64];
    const int t = threadIdx.x;
    // XCD-aware swizzle: 576 = 8 * 72 -> each XCD gets a contiguous 3-row tile band
    const int traw = blockIdx.x;
    const int tile = (traw & 7) * 72 + (traw >> 3);
    const int b = blockIdx.y;
    const int ty0 = (tile / 24) * 8, tx0 = (tile % 24) * 8;
    const int lane = t & 63;
    const int og = __builtin_amdgcn_readfirstlane(t >> 6);
    const int l15 = lane & 15, l4 = lane >> 4;
    const int ys0 = (ty0 >> 2) - 1, xs0 = (tx0 >> 2) - 1;

    f32x4 acc[4];
#pragma unroll
    for (int n = 0; n < 4; ++n) acc[n] = (f32x4){0.f, 0.f, 0.f, 0.f};

    // p-wise resize cells/weights (group/tap independent)
    if (t < 64) {
        int p = t;
        int y = ty0 + (p >> 3), xx = tx0 + (p & 7);
        float ysf = fminf(fmaxf((y + 0.5f) * 0.25f - 0.5f, 0.f), 47.f);
        float xsf = fminf(fmaxf((xx + 0.5f) * 0.25f - 0.5f, 0.f), 47.f);
        int ry0 = (int)ysf, rx0 = (int)xsf;
        float fy = ysf - (float)ry0, fx = xsf - (float)rx0;
        rb[p] = (ry0 - ys0) * 4 + (rx0 - xs0);
        rw[0][p] = (1.f - fy) * (1.f - fx);
        rw[1][p] = (1.f - fy) * fx;
        rw[2][p] = fy * (1.f - fx);
        rw[3][p] = fy * fx;
    }
    // zero K-pad units (cols 72..95) of all 4 val buffers
    for (int i = t; i < 768; i += 512) {
        int bb = i / 192; int j = i - bb * 192;
        int row = j / 3, un = 9 + j % 3;
        *reinterpret_cast<uint4*>(&val[bb][row * 104 + un * 8]) = make_uint4(0, 0, 0, 0);
    }

    const float* a4b = a4 + (size_t)b * C4 * HWS;
    const float* flb = flow + (size_t)b * 32 * HW;
    const u16* xgb0 = xg + (size_t)b * DG_ * HW * 8;

#define STAGE(gg, bb) do {                                                          \
    const int gk = (gg);                                                            \
    if (t < 432) {                                                                  \
        int ch = t >> 4, idx = t & 15;                                              \
        int gy = min(max(ys0 + (idx >> 2), 0), 47);                                 \
        int gx = min(max(xs0 + (idx & 3), 0), 47);                                  \
        int a4ch = (ch < 18) ? (gk * 18 + ch) : (288 + gk * 9 + (ch - 18));         \
        a4t[bb][t] = a4b[(size_t)a4ch * HWS + gy * 48 + gx];                        \
    }                                                                               \
    if (t < 128) {                                                                  \
        int comp = t >> 6, p = t & 63;                                              \
        int y = ty0 + (p >> 3), xx = tx0 + (p & 7);                                 \
        flds[bb][t] = flb[(size_t)(2 * gk + 1 - comp) * HW + y * WW + xx];          \
    }                                                                               \
} while (0)

#define PH12(gg, bb) do {                                                           \
    const u16* xgb = xgb0 + (size_t)(gg) * HW * 8;                                  \
    for (int i = t; i < 576; i += 512) {                                            \
        int k = i >> 6, p = i & 63;                                                 \
        int y = ty0 + (p >> 3), xx = tx0 + (p & 7);                                 \
        int base = rb[p];                                                           \
        float r00 = rw[0][p], r01 = rw[1][p], r10 = rw[2][p], r11 = rw[3][p];       \
        const float* A = &a4t[bb][0];                                               \
        float sdy = A[(2*k)*16+base]*r00 + A[(2*k)*16+base+1]*r01                   \
                  + A[(2*k)*16+base+4]*r10 + A[(2*k)*16+base+5]*r11;                \
        float sdx = A[(2*k+1)*16+base]*r00 + A[(2*k+1)*16+base+1]*r01               \
                  + A[(2*k+1)*16+base+4]*r10 + A[(2*k+1)*16+base+5]*r11;            \
        float sm  = A[(18+k)*16+base]*r00 + A[(18+k)*16+base+1]*r01                 \
                  + A[(18+k)*16+base+4]*r10 + A[(18+k)*16+base+5]*r11;              \
        float dyv = 5.f * tanh_fast(sdy) + flds[bb][p];                             \
        float dxv = 5.f * tanh_fast(sdx) + flds[bb][64 + p];                        \
        float m = sigmoid_fast(sm);                                                 \
        float fpy = (float)(y + (k / 3) - 1) + dyv;                                 \
        float fpx = (float)(xx + (k % 3) - 1) + dxv;                                \
        float y0f = floorf(fpy), x0f = floorf(fpx);                                 \
        int gy0 = (int)y0f, gx0 = (int)x0f;                                         \
        int gy1 = gy0 + 1, gx1 = gx0 + 1;                                           \
        float wy = fpy - y0f, wx = fpx - x0f;                                       \
        bool by0 = (unsigned)gy0 < (unsigned)HH, by1 = (unsigned)gy1 < (unsigned)HH;\
        bool bx0 = (unsigned)gx0 < (unsigned)WW, bx1 = (unsigned)gx1 < (unsigned)WW;\
        int y0c = min(max(gy0, 0), HH - 1), y1c = min(max(gy1, 0), HH - 1);         \
        int x0c = min(max(gx0, 0), WW - 1), x1c = min(max(gx1, 0), WW - 1);         \
        float w00 = (by0 && bx0) ? (1.f - wy) * (1.f - wx) * m : 0.f;               \
        float w01 = (by0 && bx1) ? (1.f - wy) * wx * m : 0.f;                       \
        float w10 = (by1 && bx0) ? wy * (1.f - wx) * m : 0.f;                       \
        float w11 = (by1 && bx1) ? wy * wx * m : 0.f;                               \
        uint4 v00 = *reinterpret_cast<const uint4*>(&xgb[(size_t)(y0c * WW + x0c) * 8]); \
        uint4 v01 = *reinterpret_cast<const uint4*>(&xgb[(size_t)(y0c * WW + x1c) * 8]); \
        uint4 v10 = *reinterpret_cast<const uint4*>(&xgb[(size_t)(y1c * WW + x0c) * 8]); \
        uint4 v11 = *reinterpret_cast<const uint4*>(&xgb[(size_t)(y1c * WW + x1c) * 8]); \
        const __half2* h00 = reinterpret_cast<const __half2*>(&v00);                \
        const __half2* h01 = reinterpret_cast<const __half2*>(&v01);                \
        const __half2* h10 = reinterpret_cast<const __half2*>(&v10);                \
        const __half2* h11 = reinterpret_cast<const __half2*>(&v11);                \
        __half hw00 = __float2half_rn(w00), hw01 = __float2half_rn(w01);            \
        __half hw10 = __float2half_rn(w10), hw11 = __float2half_rn(w11);            \
        __half2 W00{hw00, hw00}, W01{hw01, hw01}, W10{hw10, hw10}, W11{hw11, hw11}; \
        union { __half2 h2[4]; uint4 u4; } uu;                                      \
        _Pragma("unroll")                                                           \
        for (int cc = 0; cc < 4; ++cc)                                              \
            uu.h2[cc] = __hfma2(h00[cc], W00, __hfma2(h01[cc], W01,                 \
                        __hfma2(h10[cc], W10, __hmul2(h11[cc], W11))));             \
        *reinterpret_cast<uint4*>(&val[bb][p * 104 + k * 8]) = uu.u4;               \
    }                                                                               \
} while (0)

    STAGE(0, 0);
    STAGE(1, 1);
    __syncthreads();

    for (int pr = 0; pr < 8; ++pr) {
        const int g0 = 2 * pr, g1 = 2 * pr + 1;
        const int b0 = g0 & 3, b1 = g1 & 3;
        PH12(g0, b0);
        PH12(g1, b1);
        if (pr < 7) {
            STAGE(g0 + 2, (g0 + 2) & 3);
            STAGE(g1 + 2, (g1 + 2) & 3);
        }
        __syncthreads();
        __builtin_amdgcn_s_setprio(1);
#pragma unroll
        for (int h = 0; h < 2; ++h) {
            const int gh = 2 * pr + h;
            const u16* wg = wA + (size_t)(og * 16) * 1536 + gh * 96;
            const u16* vb = &val[gh & 3][0];
#pragma unroll
            for (int kb = 0; kb < 3; ++kb) {
                f16x8 a = *reinterpret_cast<const f16x8*>(wg + (size_t)l15 * 1536 + kb * 32 + l4 * 8);
#pragma unroll
                for (int nf = 0; nf < 4; ++nf) {
                    int row = nf * 16 + l15;
                    f16x8 bfrag = *reinterpret_cast<const f16x8*>(
                        &vb[row * 104 + kb * 32 + l4 * 8]);
                    acc[nf] = __builtin_amdgcn_mfma_f32_16x16x32_f16(a, bfrag, acc[nf], 0, 0, 0);
                }
            }
        }
        __builtin_amdgcn_s_setprio(0);
    }
#undef STAGE
#undef PH12
    // epilogue: D col=lane&15 (pixel), row=(lane>>4)*4+reg (oc within 16)
#pragma unroll
    for (int nf = 0; nf < 4; ++nf) {
        int pix = nf * 16 + l15;
        int py = ty0 + (pix >> 3), px = tx0 + (pix & 7);
#pragma unroll
        for (int r = 0; r < 4; ++r) {
            int o = og * 16 + l4 * 4 + r;
            out[((size_t)(b * COUT_D + o) * HH + py) * WW + px] = acc[nf][r] + bias[o];
        }
    }
}

extern "C" void kernel_launch(void* const* d_in, const int* in_sizes, int n_in,
                              void* d_out, int out_size, void* d_ws, size_t ws_size,
                              hipStream_t stream) {
    const float* x    = (const float*)d_in[0];
    const float* flow = (const float*)d_in[1];
    const float* addf = (const float*)d_in[2];
    const float* w1   = (const float*)d_in[3];
    const float* b1   = (const float*)d_in[4];
    const float* w2   = (const float*)d_in[5];
    const float* b2   = (const float*)d_in[6];
    const float* w3   = (const float*)d_in[7];
    const float* b3   = (const float*)d_in[8];
    const float* w4   = (const float*)d_in[9];
    const float* b4   = (const float*)d_in[10];
    const float* wgt  = (const float*)d_in[11];
    const float* bias = (const float*)d_in[12];
    float* out = (float*)d_out;
    float* ws = (float*)d_ws;

    float* zp    = ws;                               // 256 f32
    u16*  pool_t = (u16*)(ws + 256);                 // 1,474,560 u16
    u16*  c1     = pool_t + 1474560;                 // 589,824 u16
    u16*  c2     = c1 + 589824;                      // 589,824 u16
    u16*  c3     = c1;                               // alias (c1 dead after conv2)
    float* a4    = (float*)(c2 + 589824);            // 1,990,656 f32
    u16*  wq1    = (u16*)(a4 + 1990656);             // 184,320 u16
    u16*  wq2    = wq1 + 184320;                     // 73,728
    u16*  wq3    = wq2 + 73728;                      // 73,728
    u16*  wq4    = wq3 + 73728;                      // 516,096
    u16*  wA     = wq4 + 516096;                     // 196,608 (fp16)
    u16*  xg     = wA + 196608;                      // 9,437,184 (fp16)

    fused_prep_kernel      <<<4081, 256, 0, stream>>>(w1, w2, w3, w4, wgt, zp, wq1, wq2, wq3, wq4, wA);
    fused_trans_pool_kernel<<<7488, 256, 0, stream>>>(x, flow, addf, xg, pool_t);

    conv_ks<160, 12, 23, 34, 45, true><<<dim3(144, 1, 2), 1024, 0, stream>>>(pool_t, wq1, b1, c1);
    conv_ks<64,  5,  10, 14, 18, true><<<dim3(144, 1, 2), 1024, 0, stream>>>(c1, wq2, b2, c2);
    conv_ks<64,  5,  10, 14, 18, true><<<dim3(144, 1, 2), 1024, 0, stream>>>(c2, wq3, b3, c3);
    conv_mfma<64, 432, 448, false><<<dim3(144, 7, 2), 256, 0, stream>>>(c3, wq4, b4, a4);

    deform_mfma<<<dim3(576, 2), 512, 0, stream>>>(xg, flow, a4, wA, bias, out);
}

// Round 13
// 220.653 us; speedup vs baseline: 1.3532x; 1.0805x over previous
//
#include <hip/hip_runtime.h>
#include <hip/hip_fp16.h>

#define B_ 2
#define CX 64
#define HH 192
#define WW 192
#define HW (HH*WW)
#define HS 48
#define WS 48
#define HWS (HS*WS)
#define CE 160
#define C4 432
#define DG_ 16
#define COUT_D 128

typedef short bf16x8 __attribute__((ext_vector_type(8)));
typedef _Float16 f16x8 __attribute__((ext_vector_type(8)));
typedef float f32x4 __attribute__((ext_vector_type(4)));
typedef unsigned short u16;

__device__ __forceinline__ unsigned f2bf(float f) {
    unsigned u = __float_as_uint(f);
    return (u + 0x7FFFu + ((u >> 16) & 1u)) >> 16;   // RNE
}
__device__ __forceinline__ float bf2f(u16 h) {
    return __uint_as_float(((unsigned)h) << 16);
}
__device__ __forceinline__ void split_hl(float v, u16& h, u16& l) {
    h = (u16)f2bf(v);
    l = (u16)f2bf(v - bf2f(h));
}
__device__ __forceinline__ float tanh_fast(float v) {
    float e = __expf(2.f * v);
    return 1.f - 2.f * __builtin_amdgcn_rcpf(e + 1.f);
}
__device__ __forceinline__ float sigmoid_fast(float s) {
    return __builtin_amdgcn_rcpf(1.f + __expf(-s));
}

// ---------------- fused prep: zp + wq1..wq4 + wA ----------------
__device__ __forceinline__ void prep_wq_body(const float* __restrict__ w, u16* __restrict__ wq,
                                             int i, int OC, int OCP, int CIN) {
    int ic = i % CIN; int rest = i / CIN;
    int oc = rest % OCP; rest /= OCP;
    int q = rest % 9; int kind = rest / 9;
    float v = (oc < OC) ? w[((size_t)oc * CIN + ic) * 9 + q] : 0.f;
    u16 h, l; split_hl(v, h, l);
    wq[i] = kind ? l : h;
}

__global__ void fused_prep_kernel(const float* __restrict__ w1, const float* __restrict__ w2,
                                  const float* __restrict__ w3, const float* __restrict__ w4,
                                  const float* __restrict__ wgt,
                                  float* __restrict__ zp, u16* __restrict__ wq1,
                                  u16* __restrict__ wq2, u16* __restrict__ wq3,
                                  u16* __restrict__ wq4, u16* __restrict__ wA) {
    int bid = blockIdx.x, t = threadIdx.x;
    if (bid == 0) { zp[t] = 0.f; return; }
    if (bid < 721)  { prep_wq_body(w1, wq1, (bid - 1) * 256 + t, 64, 64, 160); return; }
    if (bid < 1009) { prep_wq_body(w2, wq2, (bid - 721) * 256 + t, 64, 64, 64); return; }
    if (bid < 1297) { prep_wq_body(w3, wq3, (bid - 1009) * 256 + t, 64, 64, 64); return; }
    if (bid < 3313) { prep_wq_body(w4, wq4, (bid - 1297) * 256 + t, 432, 448, 64); return; }
    // wA fp16: [o][g*96 + tap*8 + c], taps 9..11 = 0
    int i = (bid - 3313) * 256 + t;                  // 128*1536 = 768*256
    int o = i / 1536, col = i - o * 1536;
    int g = col / 96, r = col - g * 96;
    int tap = r >> 3, c = r & 7;
    float v = (tap < 9) ? wgt[(size_t)o * 1152 + (g * 8 + c) * 9 + tap] : 0.f;
    wA[i] = __half_as_ushort(__float2half_rn(v));
}

// ---------------- fused: x/addf -> NHWC fp16 xg ; avgpool4+concat -> pool_t ----------------
__global__ void fused_trans_pool_kernel(const float* __restrict__ x, const float* __restrict__ flow,
                                        const float* __restrict__ addf,
                                        u16* __restrict__ xg, u16* __restrict__ pt) {
    int bid = blockIdx.x, t = threadIdx.x;
    if (bid < 4608) {
        int i = bid * 256 + t;                       // 2*16*36864
        int p = i % HW;
        int g = (i / HW) % DG_;
        int b = i / (HW * DG_);
        const float* xb = x    + ((size_t)(b * CX + g * 4)) * HW + p;
        const float* ab = addf + ((size_t)(b * CX + g * 4)) * HW + p;
        __half2 h[4];
        h[0].x = __float2half_rn(xb[0]);      h[0].y = __float2half_rn(xb[HW]);
        h[1].x = __float2half_rn(xb[2 * HW]); h[1].y = __float2half_rn(xb[3 * HW]);
        h[2].x = __float2half_rn(ab[0]);      h[2].y = __float2half_rn(ab[HW]);
        h[3].x = __float2half_rn(ab[2 * HW]); h[3].y = __float2half_rn(ab[3 * HW]);
        *reinterpret_cast<uint4*>(&xg[(size_t)i * 8]) = *reinterpret_cast<uint4*>(h);
    } else {
        int i = (bid - 4608) * 256 + t;              // 737280
        int xs = i % WS, ys = (i / WS) % HS, c = (i / HWS) % CE, b = i / (HWS * CE);
        const float* src;
        if (c < 64)      src = x    + (size_t)(b * 64 + c) * HW;
        else if (c < 96) src = flow + (size_t)(b * 32 + (c - 64)) * HW;
        else             src = addf + (size_t)(b * 64 + (c - 96)) * HW;
        const float4* s4 = reinterpret_cast<const float4*>(src + (ys * 4) * WW + xs * 4);
        float sum = 0.f;
#pragma unroll
        for (int r = 0; r < 4; ++r) {
            float4 v = s4[r * (WW / 4)];
            sum += v.x + v.y + v.z + v.w;
        }
        float v = sum * (1.f / 16.f);
        u16 h, l; split_hl(v, h, l);
        size_t base = ((size_t)(b * HWS + ys * WS + xs) * 2) * CE + c;
        pt[base] = h; pt[base + CE] = l;
    }
}

// ---------------- 4-way K-split MFMA 3x3 conv (64 oc), LDS-staged input tile ----------------
template<int CIN, int U0, int U1, int U2, int UT, bool LRELU>
__global__ __launch_bounds__(1024) void conv_ks(const u16* __restrict__ in_t,
                                                const u16* __restrict__ wq,
                                                const float* __restrict__ bias,
                                                u16* __restrict__ out_t) {
    constexpr int CP = CIN + 4;                      // padded channel stride (bank de-alias)
    __shared__ u16 tile_in[36 * 2 * CP];             // [spx 6x6][kind hi/lo][c]
    __shared__ float red[3 * 4 * 256];               // [ks-1][ocgrp][r*64+lane]
    const int t = threadIdx.x;
    const int w = t >> 6;
    const int ocgrp = w & 3, ks = w >> 2;
    const int lane = t & 63;
    const int l15 = t & 15, l4 = (t >> 4) & 3;
    const int tile = blockIdx.x;
    const int ty0 = (tile / 12) * 4, tx0 = (tile % 12) * 4;
    const int b = blockIdx.z;
    const int ocb = ocgrp * 16;
    const int py = ty0 + (l15 >> 2), pxx = tx0 + (l15 & 3);
    const u16* inb = in_t + (size_t)b * (HWS * 2 * CIN);

    // stage 6x6 halo (zero-padded), coalesced uint4
    for (int i = t; i < 36 * 2 * (CIN / 8); i += 1024) {
        int c8 = i % (CIN / 8); int rest = i / (CIN / 8);
        int kind = rest & 1; int spx = rest >> 1;
        int gy = ty0 - 1 + spx / 6, gx = tx0 - 1 + spx % 6;
        uint4 v = make_uint4(0, 0, 0, 0);
        if ((unsigned)gy < 48u && (unsigned)gx < 48u)
            v = *reinterpret_cast<const uint4*>(&inb[((size_t)(gy * 48 + gx) * 2 + kind) * CIN + c8 * 8]);
        *reinterpret_cast<uint4*>(&tile_in[(spx * 2 + kind) * CP + c8 * 8]) = v;
    }
    __syncthreads();

    f32x4 ahh = {0,0,0,0}, ahl = {0,0,0,0}, alh = {0,0,0,0};
    constexpr int KB = CIN / 32;
    const int lpy = l15 >> 2, lpx = l15 & 3;

#define CONV_BODY(US, UE)                                                             \
    _Pragma("unroll")                                                                 \
    for (int u = (US); u < (UE); ++u) {                                               \
        const int q = u / KB, kb = u % KB;                                            \
        const int spx = (lpy + q / 3) * 6 + (lpx + q % 3);                            \
        const u16* bh = &tile_in[(spx * 2 + 0) * CP + kb * 32 + l4 * 8];              \
        const u16* bl = &tile_in[(spx * 2 + 1) * CP + kb * 32 + l4 * 8];              \
        const u16* wh = wq + ((size_t)q * 64 + ocb + l15) * CIN + l4 * 8 + kb * 32;   \
        const u16* wl = wh + (size_t)9 * 64 * CIN;                                    \
        bf16x8 Ah = *reinterpret_cast<const bf16x8*>(wh);                             \
        bf16x8 Al = *reinterpret_cast<const bf16x8*>(wl);                             \
        bf16x8 Bh = *reinterpret_cast<const bf16x8*>(bh);                             \
        bf16x8 Bl = *reinterpret_cast<const bf16x8*>(bl);                             \
        ahh = __builtin_amdgcn_mfma_f32_16x16x32_bf16(Ah, Bh, ahh, 0, 0, 0);          \
        ahl = __builtin_amdgcn_mfma_f32_16x16x32_bf16(Ah, Bl, ahl, 0, 0, 0);          \
        alh = __builtin_amdgcn_mfma_f32_16x16x32_bf16(Al, Bh, alh, 0, 0, 0);          \
    }
    if (ks == 0)      { CONV_BODY(0,  U0) }
    else if (ks == 1) { CONV_BODY(U0, U1) }
    else if (ks == 2) { CONV_BODY(U1, U2) }
    else              { CONV_BODY(U2, UT) }
#undef CONV_BODY

    float vsum[4];
#pragma unroll
    for (int r = 0; r < 4; ++r) vsum[r] = ahh[r] + ahl[r] + alh[r];
    if (ks) {
#pragma unroll
        for (int r = 0; r < 4; ++r)
            red[((ks - 1) * 4 + ocgrp) * 256 + r * 64 + lane] = vsum[r];
    }
    __syncthreads();
    if (!ks) {
#pragma unroll
        for (int r = 0; r < 4; ++r) {
#pragma unroll
            for (int j = 0; j < 3; ++j)
                vsum[r] += red[(j * 4 + ocgrp) * 256 + r * 64 + lane];
            int oc = ocb + l4 * 4 + r;
            float v = vsum[r] + bias[oc];
            if (LRELU) v = (v >= 0.f) ? v : 0.2f * v;
            u16 h, l; split_hl(v, h, l);
            size_t base = ((size_t)(b * HWS + py * 48 + pxx) * 2) * 64 + oc;
            out_t[base] = h; out_t[base + 64] = l;
        }
    }
}

// ---------------- MFMA 3x3 conv (conv4: 432 oc, f32 out), 4 waves, LDS-staged tile ----------------
template<int CIN, int OC, int OCP, bool LRELU>
__global__ __launch_bounds__(256) void conv_mfma(const u16* __restrict__ in_t,
                                                 const u16* __restrict__ wq,
                                                 const float* __restrict__ bias,
                                                 float* __restrict__ out_f) {
    constexpr int CP = CIN + 4;
    __shared__ u16 tile_in[36 * 2 * CP];             // 9.8 KB for CIN=64
    const int t = threadIdx.x;
    const int wv = __builtin_amdgcn_readfirstlane(t >> 6);
    const int l15 = t & 15, l4 = (t >> 4) & 3;
    const int tile = blockIdx.x;
    const int ty0 = (tile / 12) * 4, tx0 = (tile % 12) * 4;
    const int ocb = blockIdx.y * 64 + wv * 16;
    const int b = blockIdx.z;
    const int py = ty0 + (l15 >> 2), pxx = tx0 + (l15 & 3);
    const u16* inb = in_t + (size_t)b * (HWS * 2 * CIN);

    for (int i = t; i < 36 * 2 * (CIN / 8); i += 256) {
        int c8 = i % (CIN / 8); int rest = i / (CIN / 8);
        int kind = rest & 1; int spx = rest >> 1;
        int gy = ty0 - 1 + spx / 6, gx = tx0 - 1 + spx % 6;
        uint4 v = make_uint4(0, 0, 0, 0);
        if ((unsigned)gy < 48u && (unsigned)gx < 48u)
            v = *reinterpret_cast<const uint4*>(&inb[((size_t)(gy * 48 + gx) * 2 + kind) * CIN + c8 * 8]);
        *reinterpret_cast<uint4*>(&tile_in[(spx * 2 + kind) * CP + c8 * 8]) = v;
    }
    __syncthreads();

    f32x4 ahh = {0,0,0,0}, ahl = {0,0,0,0}, alh = {0,0,0,0};
    const int lpy = l15 >> 2, lpx = l15 & 3;
#pragma unroll
    for (int q = 0; q < 9; ++q) {
        const int spx = (lpy + q / 3) * 6 + (lpx + q % 3);
        const u16* bh = &tile_in[(spx * 2 + 0) * CP];
        const u16* bl = &tile_in[(spx * 2 + 1) * CP];
        const u16* wh = wq + ((size_t)q * OCP + ocb + l15) * CIN + l4 * 8;
        const u16* wl = wq + ((size_t)(9 + q) * OCP + ocb + l15) * CIN + l4 * 8;
#pragma unroll
        for (int kb = 0; kb < CIN / 32; ++kb) {
            bf16x8 Ah = *reinterpret_cast<const bf16x8*>(wh + kb * 32);
            bf16x8 Al = *reinterpret_cast<const bf16x8*>(wl + kb * 32);
            bf16x8 Bh = *reinterpret_cast<const bf16x8*>(bh + kb * 32 + l4 * 8);
            bf16x8 Bl = *reinterpret_cast<const bf16x8*>(bl + kb * 32 + l4 * 8);
            ahh = __builtin_amdgcn_mfma_f32_16x16x32_bf16(Ah, Bh, ahh, 0, 0, 0);
            ahl = __builtin_amdgcn_mfma_f32_16x16x32_bf16(Ah, Bl, ahl, 0, 0, 0);
            alh = __builtin_amdgcn_mfma_f32_16x16x32_bf16(Al, Bh, alh, 0, 0, 0);
        }
    }
#pragma unroll
    for (int r = 0; r < 4; ++r) {
        int oc = ocb + l4 * 4 + r;
        float v = ahh[r] + ahl[r] + alh[r] + ((oc < OC) ? bias[oc] : 0.f);
        if (LRELU) v = (v >= 0.f) ? v : 0.2f * v;
        if (oc < OC) out_f[((size_t)(b * OC + oc)) * HWS + py * 48 + pxx] = v;
    }
}

// ---------------- deform (R9 exact — best measured): R5 skeleton + setprio + XCD swizzle ----------------
__global__ __launch_bounds__(512) void deform_mfma(
    const u16* __restrict__ xg, const float* __restrict__ flow,
    const float* __restrict__ a4, const u16* __restrict__ wA,
    const float* __restrict__ bias, float* __restrict__ out)
{
    __shared__ u16 val[2][64 * 104];                 // fp16 [pixel][ck pad 96->104]
    __shared__ float a4t[2][27 * 16];
    __shared__ float flds[2][128];
    __shared__ float rw[4][64];
    __shared__ int rb[64];
    const int t = threadIdx.x;
    // XCD-aware swizzle: 576 = 8 * 72 -> each XCD gets a contiguous 3-row tile band
    const int traw = blockIdx.x;
    const int tile = (traw & 7) * 72 + (traw >> 3);
    const int b = blockIdx.y;
    const int ty0 = (tile / 24) * 8, tx0 = (tile % 24) * 8;
    const int lane = t & 63;
    const int og = __builtin_amdgcn_readfirstlane(t >> 6);
    const int l15 = lane & 15, l4 = lane >> 4;
    const int ys0 = (ty0 >> 2) - 1, xs0 = (tx0 >> 2) - 1;

    f32x4 acc[4];
#pragma unroll
    for (int n = 0; n < 4; ++n) acc[n] = (f32x4){0.f, 0.f, 0.f, 0.f};

    // p-wise resize cells/weights (group/tap independent)
    if (t < 64) {
        int p = t;
        int y = ty0 + (p >> 3), xx = tx0 + (p & 7);
        float ysf = fminf(fmaxf((y + 0.5f) * 0.25f - 0.5f, 0.f), 47.f);
        float xsf = fminf(fmaxf((xx + 0.5f) * 0.25f - 0.5f, 0.f), 47.f);
        int ry0 = (int)ysf, rx0 = (int)xsf;
        float fy = ysf - (float)ry0, fx = xsf - (float)rx0;
        rb[p] = (ry0 - ys0) * 4 + (rx0 - xs0);
        rw[0][p] = (1.f - fy) * (1.f - fx);
        rw[1][p] = (1.f - fy) * fx;
        rw[2][p] = fy * (1.f - fx);
        rw[3][p] = fy * fx;
    }
    // zero K-pad units (cols 72..95) of both val buffers
    if (t < 384) {
        int bb = (t >= 192) ? 1 : 0; int j = t - bb * 192;
        int row = j / 3, un = 9 + j % 3;
        *reinterpret_cast<uint4*>(&val[bb][row * 104 + un * 8]) = make_uint4(0, 0, 0, 0);
    }

    const float* a4b = a4 + (size_t)b * C4 * HWS;
    const float* flb = flow + (size_t)b * 32 * HW;
    const u16* xgb0 = xg + (size_t)b * DG_ * HW * 8;

#define STAGE(gg, bb) do {                                                          \
    const int gk = (gg);                                                            \
    if (t < 432) {                                                                  \
        int ch = t >> 4, idx = t & 15;                                              \
        int gy = min(max(ys0 + (idx >> 2), 0), 47);                                 \
        int gx = min(max(xs0 + (idx & 3), 0), 47);                                  \
        int a4ch = (ch < 18) ? (gk * 18 + ch) : (288 + gk * 9 + (ch - 18));         \
        a4t[bb][t] = a4b[(size_t)a4ch * HWS + gy * 48 + gx];                        \
    }                                                                               \
    if (t < 128) {                                                                  \
        int comp = t >> 6, p = t & 63;                                              \
        int y = ty0 + (p >> 3), xx = tx0 + (p & 7);                                 \
        flds[bb][t] = flb[(size_t)(2 * gk + 1 - comp) * HW + y * WW + xx];          \
    }                                                                               \
} while (0)

#define PH12(gg, bb) do {                                                           \
    const u16* xgb = xgb0 + (size_t)(gg) * HW * 8;                                  \
    for (int i = t; i < 576; i += 512) {                                            \
        int k = i >> 6, p = i & 63;                                                 \
        int y = ty0 + (p >> 3), xx = tx0 + (p & 7);                                 \
        int base = rb[p];                                                           \
        float r00 = rw[0][p], r01 = rw[1][p], r10 = rw[2][p], r11 = rw[3][p];       \
        const float* A = &a4t[bb][0];                                               \
        float sdy = A[(2*k)*16+base]*r00 + A[(2*k)*16+base+1]*r01                   \
                  + A[(2*k)*16+base+4]*r10 + A[(2*k)*16+base+5]*r11;                \
        float sdx = A[(2*k+1)*16+base]*r00 + A[(2*k+1)*16+base+1]*r01               \
                  + A[(2*k+1)*16+base+4]*r10 + A[(2*k+1)*16+base+5]*r11;            \
        float sm  = A[(18+k)*16+base]*r00 + A[(18+k)*16+base+1]*r01                 \
                  + A[(18+k)*16+base+4]*r10 + A[(18+k)*16+base+5]*r11;              \
        float dyv = 5.f * tanh_fast(sdy) + flds[bb][p];                             \
        float dxv = 5.f * tanh_fast(sdx) + flds[bb][64 + p];                        \
        float m = sigmoid_fast(sm);                                                 \
        float fpy = (float)(y + (k / 3) - 1) + dyv;                                 \
        float fpx = (float)(xx + (k % 3) - 1) + dxv;                                \
        float y0f = floorf(fpy), x0f = floorf(fpx);                                 \
        int gy0 = (int)y0f, gx0 = (int)x0f;                                         \
        int gy1 = gy0 + 1, gx1 = gx0 + 1;                                           \
        float wy = fpy - y0f, wx = fpx - x0f;                                       \
        bool by0 = (unsigned)gy0 < (unsigned)HH, by1 = (unsigned)gy1 < (unsigned)HH;\
        bool bx0 = (unsigned)gx0 < (unsigned)WW, bx1 = (unsigned)gx1 < (unsigned)WW;\
        int y0c = min(max(gy0, 0), HH - 1), y1c = min(max(gy1, 0), HH - 1);         \
        int x0c = min(max(gx0, 0), WW - 1), x1c = min(max(gx1, 0), WW - 1);         \
        float w00 = (by0 && bx0) ? (1.f - wy) * (1.f - wx) * m : 0.f;               \
        float w01 = (by0 && bx1) ? (1.f - wy) * wx * m : 0.f;                       \
        float w10 = (by1 && bx0) ? wy * (1.f - wx) * m : 0.f;                       \
        float w11 = (by1 && bx1) ? wy * wx * m : 0.f;                               \
        uint4 v00 = *reinterpret_cast<const uint4*>(&xgb[(size_t)(y0c * WW + x0c) * 8]); \
        uint4 v01 = *reinterpret_cast<const uint4*>(&xgb[(size_t)(y0c * WW + x1c) * 8]); \
        uint4 v10 = *reinterpret_cast<const uint4*>(&xgb[(size_t)(y1c * WW + x0c) * 8]); \
        uint4 v11 = *reinterpret_cast<const uint4*>(&xgb[(size_t)(y1c * WW + x1c) * 8]); \
        const __half2* h00 = reinterpret_cast<const __half2*>(&v00);                \
        const __half2* h01 = reinterpret_cast<const __half2*>(&v01);                \
        const __half2* h10 = reinterpret_cast<const __half2*>(&v10);                \
        const __half2* h11 = reinterpret_cast<const __half2*>(&v11);                \
        __half hw00 = __float2half_rn(w00), hw01 = __float2half_rn(w01);            \
        __half hw10 = __float2half_rn(w10), hw11 = __float2half_rn(w11);            \
        __half2 W00{hw00, hw00}, W01{hw01, hw01}, W10{hw10, hw10}, W11{hw11, hw11}; \
        union { __half2 h2[4]; uint4 u4; } uu;                                      \
        _Pragma("unroll")                                                           \
        for (int cc = 0; cc < 4; ++cc)                                              \
            uu.h2[cc] = __hfma2(h00[cc], W00, __hfma2(h01[cc], W01,                 \
                        __hfma2(h10[cc], W10, __hmul2(h11[cc], W11))));             \
        *reinterpret_cast<uint4*>(&val[bb][p * 104 + k * 8]) = uu.u4;               \
    }                                                                               \
} while (0)

    STAGE(0, 0);
    __syncthreads();

    for (int g = 0; g < DG_; ++g) {
        const int buf = g & 1;
        if (g < 15) STAGE(g + 1, buf ^ 1);
        PH12(g, buf);
        __syncthreads();
        const u16* wg = wA + (size_t)(og * 16) * 1536 + g * 96;
        __builtin_amdgcn_s_setprio(1);
#pragma unroll
        for (int kb = 0; kb < 3; ++kb) {
            f16x8 a = *reinterpret_cast<const f16x8*>(wg + (size_t)l15 * 1536 + kb * 32 + l4 * 8);
#pragma unroll
            for (int nf = 0; nf < 4; ++nf) {
                int row = nf * 16 + l15;
                f16x8 bfrag = *reinterpret_cast<const f16x8*>(
                    &val[buf][row * 104 + kb * 32 + l4 * 8]);
                acc[nf] = __builtin_amdgcn_mfma_f32_16x16x32_f16(a, bfrag, acc[nf], 0, 0, 0);
            }
        }
        __builtin_amdgcn_s_setprio(0);
    }
#undef STAGE
#undef PH12
    // epilogue: D col=lane&15 (pixel), row=(lane>>4)*4+reg (oc within 16)
#pragma unroll
    for (int nf = 0; nf < 4; ++nf) {
        int pix = nf * 16 + l15;
        int py = ty0 + (pix >> 3), px = tx0 + (pix & 7);
#pragma unroll
        for (int r = 0; r < 4; ++r) {
            int o = og * 16 + l4 * 4 + r;
            out[((size_t)(b * COUT_D + o) * HH + py) * WW + px] = acc[nf][r] + bias[o];
        }
    }
}

extern "C" void kernel_launch(void* const* d_in, const int* in_sizes, int n_in,
                              void* d_out, int out_size, void* d_ws, size_t ws_size,
                              hipStream_t stream) {
    const float* x    = (const float*)d_in[0];
    const float* flow = (const float*)d_in[1];
    const float* addf = (const float*)d_in[2];
    const float* w1   = (const float*)d_in[3];
    const float* b1   = (const float*)d_in[4];
    const float* w2   = (const float*)d_in[5];
    const float* b2   = (const float*)d_in[6];
    const float* w3   = (const float*)d_in[7];
    const float* b3   = (const float*)d_in[8];
    const float* w4   = (const float*)d_in[9];
    const float* b4   = (const float*)d_in[10];
    const float* wgt  = (const float*)d_in[11];
    const float* bias = (const float*)d_in[12];
    float* out = (float*)d_out;
    float* ws = (float*)d_ws;

    float* zp    = ws;                               // 256 f32
    u16*  pool_t = (u16*)(ws + 256);                 // 1,474,560 u16
    u16*  c1     = pool_t + 1474560;                 // 589,824 u16
    u16*  c2     = c1 + 589824;                      // 589,824 u16
    u16*  c3     = c1;                               // alias (c1 dead after conv2)
    float* a4    = (float*)(c2 + 589824);            // 1,990,656 f32
    u16*  wq1    = (u16*)(a4 + 1990656);             // 184,320 u16
    u16*  wq2    = wq1 + 184320;                     // 73,728
    u16*  wq3    = wq2 + 73728;                      // 73,728
    u16*  wq4    = wq3 + 73728;                      // 516,096
    u16*  wA     = wq4 + 516096;                     // 196,608 (fp16)
    u16*  xg     = wA + 196608;                      // 9,437,184 (fp16)

    fused_prep_kernel      <<<4081, 256, 0, stream>>>(w1, w2, w3, w4, wgt, zp, wq1, wq2, wq3, wq4, wA);
    fused_trans_pool_kernel<<<7488, 256, 0, stream>>>(x, flow, addf, xg, pool_t);

    conv_ks<160, 12, 23, 34, 45, true><<<dim3(144, 1, 2), 1024, 0, stream>>>(pool_t, wq1, b1, c1);
    conv_ks<64,  5,  10, 14, 18, true><<<dim3(144, 1, 2), 1024, 0, stream>>>(c1, wq2, b2, c2);
    conv_ks<64,  5,  10, 14, 18, true><<<dim3(144, 1, 2), 1024, 0, stream>>>(c2, wq3, b3, c3);
    conv_mfma<64, 432, 448, false><<<dim3(144, 7, 2), 256, 0, stream>>>(c3, wq4, b4, a4);

    deform_mfma<<<dim3(576, 2), 512, 0, stream>>>(xg, flow, a4, wA, bias, out);
}

// Round 14
// 217.149 us; speedup vs baseline: 1.3750x; 1.0161x over previous
//
#include <hip/hip_runtime.h>
#include <hip/hip_fp16.h>

#define B_ 2
#define CX 64
#define HH 192
#define WW 192
#define HW (HH*WW)
#define HS 48
#define WS 48
#define HWS (HS*WS)
#define CE 160
#define C4 432
#define DG_ 16
#define COUT_D 128

typedef short bf16x8 __attribute__((ext_vector_type(8)));
typedef _Float16 f16x8 __attribute__((ext_vector_type(8)));
typedef float f32x4 __attribute__((ext_vector_type(4)));
typedef unsigned short u16;

__device__ __forceinline__ unsigned f2bf(float f) {
    unsigned u = __float_as_uint(f);
    return (u + 0x7FFFu + ((u >> 16) & 1u)) >> 16;   // RNE
}
__device__ __forceinline__ float bf2f(u16 h) {
    return __uint_as_float(((unsigned)h) << 16);
}
__device__ __forceinline__ void split_hl(float v, u16& h, u16& l) {
    h = (u16)f2bf(v);
    l = (u16)f2bf(v - bf2f(h));
}
__device__ __forceinline__ float tanh_fast(float v) {
    float e = __expf(2.f * v);
    return 1.f - 2.f * __builtin_amdgcn_rcpf(e + 1.f);
}
__device__ __forceinline__ float sigmoid_fast(float s) {
    return __builtin_amdgcn_rcpf(1.f + __expf(-s));
}

// ---------------- mega-prep: wq1..wq4 + wA + xg transpose + pool (one launch) ----------------
__device__ __forceinline__ void prep_wq_body(const float* __restrict__ w, u16* __restrict__ wq,
                                             int i, int OC, int OCP, int CIN) {
    int ic = i % CIN; int rest = i / CIN;
    int oc = rest % OCP; rest /= OCP;
    int q = rest % 9; int kind = rest / 9;
    float v = (oc < OC) ? w[((size_t)oc * CIN + ic) * 9 + q] : 0.f;
    u16 h, l; split_hl(v, h, l);
    wq[i] = kind ? l : h;
}

__global__ void mega_prep_kernel(const float* __restrict__ w1, const float* __restrict__ w2,
                                 const float* __restrict__ w3, const float* __restrict__ w4,
                                 const float* __restrict__ wgt,
                                 const float* __restrict__ x, const float* __restrict__ flow,
                                 const float* __restrict__ addf,
                                 u16* __restrict__ wq1, u16* __restrict__ wq2,
                                 u16* __restrict__ wq3, u16* __restrict__ wq4,
                                 u16* __restrict__ wA,
                                 u16* __restrict__ xg, u16* __restrict__ pt) {
    int bid = blockIdx.x, t = threadIdx.x;
    if (bid < 720)  { prep_wq_body(w1, wq1, bid * 256 + t, 64, 64, 160); return; }
    if (bid < 1008) { prep_wq_body(w2, wq2, (bid - 720) * 256 + t, 64, 64, 64); return; }
    if (bid < 1296) { prep_wq_body(w3, wq3, (bid - 1008) * 256 + t, 64, 64, 64); return; }
    if (bid < 3312) { prep_wq_body(w4, wq4, (bid - 1296) * 256 + t, 432, 448, 64); return; }
    if (bid < 4080) {
        // wA fp16: [o][g*96 + tap*8 + c], taps 9..11 = 0
        int i = (bid - 3312) * 256 + t;              // 128*1536 = 768*256
        int o = i / 1536, col = i - o * 1536;
        int g = col / 96, r = col - g * 96;
        int tap = r >> 3, c = r & 7;
        float v = (tap < 9) ? wgt[(size_t)o * 1152 + (g * 8 + c) * 9 + tap] : 0.f;
        wA[i] = __half_as_ushort(__float2half_rn(v));
        return;
    }
    if (bid < 8688) {
        int i = (bid - 4080) * 256 + t;              // 2*16*36864
        int p = i % HW;
        int g = (i / HW) % DG_;
        int b = i / (HW * DG_);
        const float* xb = x    + ((size_t)(b * CX + g * 4)) * HW + p;
        const float* ab = addf + ((size_t)(b * CX + g * 4)) * HW + p;
        __half2 h[4];
        h[0].x = __float2half_rn(xb[0]);      h[0].y = __float2half_rn(xb[HW]);
        h[1].x = __float2half_rn(xb[2 * HW]); h[1].y = __float2half_rn(xb[3 * HW]);
        h[2].x = __float2half_rn(ab[0]);      h[2].y = __float2half_rn(ab[HW]);
        h[3].x = __float2half_rn(ab[2 * HW]); h[3].y = __float2half_rn(ab[3 * HW]);
        *reinterpret_cast<uint4*>(&xg[(size_t)i * 8]) = *reinterpret_cast<uint4*>(h);
    } else {
        int i = (bid - 8688) * 256 + t;              // 737280
        int xs = i % WS, ys = (i / WS) % HS, c = (i / HWS) % CE, b = i / (HWS * CE);
        const float* src;
        if (c < 64)      src = x    + (size_t)(b * 64 + c) * HW;
        else if (c < 96) src = flow + (size_t)(b * 32 + (c - 64)) * HW;
        else             src = addf + (size_t)(b * 64 + (c - 96)) * HW;
        const float4* s4 = reinterpret_cast<const float4*>(src + (ys * 4) * WW + xs * 4);
        float sum = 0.f;
#pragma unroll
        for (int r = 0; r < 4; ++r) {
            float4 v = s4[r * (WW / 4)];
            sum += v.x + v.y + v.z + v.w;
        }
        float v = sum * (1.f / 16.f);
        u16 h, l; split_hl(v, h, l);
        size_t base = ((size_t)(b * HWS + ys * WS + xs) * 2) * CE + c;
        pt[base] = h; pt[base + CE] = l;
    }
}

// ---------------- 4-way K-split MFMA 3x3 conv (64 oc), LDS-staged input tile ----------------
template<int CIN, int U0, int U1, int U2, int UT, bool LRELU>
__global__ __launch_bounds__(1024) void conv_ks(const u16* __restrict__ in_t,
                                                const u16* __restrict__ wq,
                                                const float* __restrict__ bias,
                                                u16* __restrict__ out_t) {
    constexpr int CP = CIN + 4;                      // padded channel stride (bank de-alias)
    __shared__ u16 tile_in[36 * 2 * CP];             // [spx 6x6][kind hi/lo][c]
    __shared__ float red[3 * 4 * 256];               // [ks-1][ocgrp][r*64+lane]
    const int t = threadIdx.x;
    const int w = t >> 6;
    const int ocgrp = w & 3, ks = w >> 2;
    const int lane = t & 63;
    const int l15 = t & 15, l4 = (t >> 4) & 3;
    const int tile = blockIdx.x;
    const int ty0 = (tile / 12) * 4, tx0 = (tile % 12) * 4;
    const int b = blockIdx.z;
    const int ocb = ocgrp * 16;
    const int py = ty0 + (l15 >> 2), pxx = tx0 + (l15 & 3);
    const u16* inb = in_t + (size_t)b * (HWS * 2 * CIN);

    // stage 6x6 halo (zero-padded), coalesced uint4
    for (int i = t; i < 36 * 2 * (CIN / 8); i += 1024) {
        int c8 = i % (CIN / 8); int rest = i / (CIN / 8);
        int kind = rest & 1; int spx = rest >> 1;
        int gy = ty0 - 1 + spx / 6, gx = tx0 - 1 + spx % 6;
        uint4 v = make_uint4(0, 0, 0, 0);
        if ((unsigned)gy < 48u && (unsigned)gx < 48u)
            v = *reinterpret_cast<const uint4*>(&inb[((size_t)(gy * 48 + gx) * 2 + kind) * CIN + c8 * 8]);
        *reinterpret_cast<uint4*>(&tile_in[(spx * 2 + kind) * CP + c8 * 8]) = v;
    }
    __syncthreads();

    f32x4 ahh = {0,0,0,0}, ahl = {0,0,0,0}, alh = {0,0,0,0};
    constexpr int KB = CIN / 32;
    const int lpy = l15 >> 2, lpx = l15 & 3;

    __builtin_amdgcn_s_setprio(1);
#define CONV_BODY(US, UE)                                                             \
    _Pragma("unroll")                                                                 \
    for (int u = (US); u < (UE); ++u) {                                               \
        const int q = u / KB, kb = u % KB;                                            \
        const int spx = (lpy + q / 3) * 6 + (lpx + q % 3);                            \
        const u16* bh = &tile_in[(spx * 2 + 0) * CP + kb * 32 + l4 * 8];              \
        const u16* bl = &tile_in[(spx * 2 + 1) * CP + kb * 32 + l4 * 8];              \
        const u16* wh = wq + ((size_t)q * 64 + ocb + l15) * CIN + l4 * 8 + kb * 32;   \
        const u16* wl = wh + (size_t)9 * 64 * CIN;                                    \
        bf16x8 Ah = *reinterpret_cast<const bf16x8*>(wh);                             \
        bf16x8 Al = *reinterpret_cast<const bf16x8*>(wl);                             \
        bf16x8 Bh = *reinterpret_cast<const bf16x8*>(bh);                             \
        bf16x8 Bl = *reinterpret_cast<const bf16x8*>(bl);                             \
        ahh = __builtin_amdgcn_mfma_f32_16x16x32_bf16(Ah, Bh, ahh, 0, 0, 0);          \
        ahl = __builtin_amdgcn_mfma_f32_16x16x32_bf16(Ah, Bl, ahl, 0, 0, 0);          \
        alh = __builtin_amdgcn_mfma_f32_16x16x32_bf16(Al, Bh, alh, 0, 0, 0);          \
    }
    if (ks == 0)      { CONV_BODY(0,  U0) }
    else if (ks == 1) { CONV_BODY(U0, U1) }
    else if (ks == 2) { CONV_BODY(U1, U2) }
    else              { CONV_BODY(U2, UT) }
#undef CONV_BODY
    __builtin_amdgcn_s_setprio(0);

    float vsum[4];
#pragma unroll
    for (int r = 0; r < 4; ++r) vsum[r] = ahh[r] + ahl[r] + alh[r];
    if (ks) {
#pragma unroll
        for (int r = 0; r < 4; ++r)
            red[((ks - 1) * 4 + ocgrp) * 256 + r * 64 + lane] = vsum[r];
    }
    __syncthreads();
    if (!ks) {
#pragma unroll
        for (int r = 0; r < 4; ++r) {
#pragma unroll
            for (int j = 0; j < 3; ++j)
                vsum[r] += red[(j * 4 + ocgrp) * 256 + r * 64 + lane];
            int oc = ocb + l4 * 4 + r;
            float v = vsum[r] + bias[oc];
            if (LRELU) v = (v >= 0.f) ? v : 0.2f * v;
            u16 h, l; split_hl(v, h, l);
            size_t base = ((size_t)(b * HWS + py * 48 + pxx) * 2) * 64 + oc;
            out_t[base] = h; out_t[base + 64] = l;
        }
    }
}

// ---------------- MFMA 3x3 conv (conv4: 432 oc, f32 out), 4 waves, LDS-staged tile ----------------
template<int CIN, int OC, int OCP, bool LRELU>
__global__ __launch_bounds__(256) void conv_mfma(const u16* __restrict__ in_t,
                                                 const u16* __restrict__ wq,
                                                 const float* __restrict__ bias,
                                                 float* __restrict__ out_f) {
    constexpr int CP = CIN + 4;
    __shared__ u16 tile_in[36 * 2 * CP];             // 9.8 KB for CIN=64
    const int t = threadIdx.x;
    const int wv = __builtin_amdgcn_readfirstlane(t >> 6);
    const int l15 = t & 15, l4 = (t >> 4) & 3;
    const int tile = blockIdx.x;
    const int ty0 = (tile / 12) * 4, tx0 = (tile % 12) * 4;
    const int ocb = blockIdx.y * 64 + wv * 16;
    const int b = blockIdx.z;
    const int py = ty0 + (l15 >> 2), pxx = tx0 + (l15 & 3);
    const u16* inb = in_t + (size_t)b * (HWS * 2 * CIN);

    for (int i = t; i < 36 * 2 * (CIN / 8); i += 256) {
        int c8 = i % (CIN / 8); int rest = i / (CIN / 8);
        int kind = rest & 1; int spx = rest >> 1;
        int gy = ty0 - 1 + spx / 6, gx = tx0 - 1 + spx % 6;
        uint4 v = make_uint4(0, 0, 0, 0);
        if ((unsigned)gy < 48u && (unsigned)gx < 48u)
            v = *reinterpret_cast<const uint4*>(&inb[((size_t)(gy * 48 + gx) * 2 + kind) * CIN + c8 * 8]);
        *reinterpret_cast<uint4*>(&tile_in[(spx * 2 + kind) * CP + c8 * 8]) = v;
    }
    __syncthreads();

    f32x4 ahh = {0,0,0,0}, ahl = {0,0,0,0}, alh = {0,0,0,0};
    const int lpy = l15 >> 2, lpx = l15 & 3;
    __builtin_amdgcn_s_setprio(1);
#pragma unroll
    for (int q = 0; q < 9; ++q) {
        const int spx = (lpy + q / 3) * 6 + (lpx + q % 3);
        const u16* bh = &tile_in[(spx * 2 + 0) * CP];
        const u16* bl = &tile_in[(spx * 2 + 1) * CP];
        const u16* wh = wq + ((size_t)q * OCP + ocb + l15) * CIN + l4 * 8;
        const u16* wl = wq + ((size_t)(9 + q) * OCP + ocb + l15) * CIN + l4 * 8;
#pragma unroll
        for (int kb = 0; kb < CIN / 32; ++kb) {
            bf16x8 Ah = *reinterpret_cast<const bf16x8*>(wh + kb * 32);
            bf16x8 Al = *reinterpret_cast<const bf16x8*>(wl + kb * 32);
            bf16x8 Bh = *reinterpret_cast<const bf16x8*>(bh + kb * 32 + l4 * 8);
            bf16x8 Bl = *reinterpret_cast<const bf16x8*>(bl + kb * 32 + l4 * 8);
            ahh = __builtin_amdgcn_mfma_f32_16x16x32_bf16(Ah, Bh, ahh, 0, 0, 0);
            ahl = __builtin_amdgcn_mfma_f32_16x16x32_bf16(Ah, Bl, ahl, 0, 0, 0);
            alh = __builtin_amdgcn_mfma_f32_16x16x32_bf16(Al, Bh, alh, 0, 0, 0);
        }
    }
    __builtin_amdgcn_s_setprio(0);
#pragma unroll
    for (int r = 0; r < 4; ++r) {
        int oc = ocb + l4 * 4 + r;
        float v = ahh[r] + ahl[r] + alh[r] + ((oc < OC) ? bias[oc] : 0.f);
        if (LRELU) v = (v >= 0.f) ? v : 0.2f * v;
        if (oc < OC) out_f[((size_t)(b * OC + oc)) * HWS + py * 48 + pxx] = v;
    }
}

// ---------------- deform (R9 exact — best measured): R5 skeleton + setprio + XCD swizzle ----------------
__global__ __launch_bounds__(512) void deform_mfma(
    const u16* __restrict__ xg, const float* __restrict__ flow,
    const float* __restrict__ a4, const u16* __restrict__ wA,
    const float* __restrict__ bias, float* __restrict__ out)
{
    __shared__ u16 val[2][64 * 104];                 // fp16 [pixel][ck pad 96->104]
    __shared__ float a4t[2][27 * 16];
    __shared__ float flds[2][128];
    __shared__ float rw[4][64];
    __shared__ int rb[64];
    const int t = threadIdx.x;
    // XCD-aware swizzle: 576 = 8 * 72 -> each XCD gets a contiguous 3-row tile band
    const int traw = blockIdx.x;
    const int tile = (traw & 7) * 72 + (traw >> 3);
    const int b = blockIdx.y;
    const int ty0 = (tile / 24) * 8, tx0 = (tile % 24) * 8;
    const int lane = t & 63;
    const int og = __builtin_amdgcn_readfirstlane(t >> 6);
    const int l15 = lane & 15, l4 = lane >> 4;
    const int ys0 = (ty0 >> 2) - 1, xs0 = (tx0 >> 2) - 1;

    f32x4 acc[4];
#pragma unroll
    for (int n = 0; n < 4; ++n) acc[n] = (f32x4){0.f, 0.f, 0.f, 0.f};

    // p-wise resize cells/weights (group/tap independent)
    if (t < 64) {
        int p = t;
        int y = ty0 + (p >> 3), xx = tx0 + (p & 7);
        float ysf = fminf(fmaxf((y + 0.5f) * 0.25f - 0.5f, 0.f), 47.f);
        float xsf = fminf(fmaxf((xx + 0.5f) * 0.25f - 0.5f, 0.f), 47.f);
        int ry0 = (int)ysf, rx0 = (int)xsf;
        float fy = ysf - (float)ry0, fx = xsf - (float)rx0;
        rb[p] = (ry0 - ys0) * 4 + (rx0 - xs0);
        rw[0][p] = (1.f - fy) * (1.f - fx);
        rw[1][p] = (1.f - fy) * fx;
        rw[2][p] = fy * (1.f - fx);
        rw[3][p] = fy * fx;
    }
    // zero K-pad units (cols 72..95) of both val buffers
    if (t < 384) {
        int bb = (t >= 192) ? 1 : 0; int j = t - bb * 192;
        int row = j / 3, un = 9 + j % 3;
        *reinterpret_cast<uint4*>(&val[bb][row * 104 + un * 8]) = make_uint4(0, 0, 0, 0);
    }

    const float* a4b = a4 + (size_t)b * C4 * HWS;
    const float* flb = flow + (size_t)b * 32 * HW;
    const u16* xgb0 = xg + (size_t)b * DG_ * HW * 8;

#define STAGE(gg, bb) do {                                                          \
    const int gk = (gg);                                                            \
    if (t < 432) {                                                                  \
        int ch = t >> 4, idx = t & 15;                                              \
        int gy = min(max(ys0 + (idx >> 2), 0), 47);                                 \
        int gx = min(max(xs0 + (idx & 3), 0), 47);                                  \
        int a4ch = (ch < 18) ? (gk * 18 + ch) : (288 + gk * 9 + (ch - 18));         \
        a4t[bb][t] = a4b[(size_t)a4ch * HWS + gy * 48 + gx];                        \
    }                                                                               \
    if (t < 128) {                                                                  \
        int comp = t >> 6, p = t & 63;                                              \
        int y = ty0 + (p >> 3), xx = tx0 + (p & 7);                                 \
        flds[bb][t] = flb[(size_t)(2 * gk + 1 - comp) * HW + y * WW + xx];          \
    }                                                                               \
} while (0)

#define PH12(gg, bb) do {                                                           \
    const u16* xgb = xgb0 + (size_t)(gg) * HW * 8;                                  \
    for (int i = t; i < 576; i += 512) {                                            \
        int k = i >> 6, p = i & 63;                                                 \
        int y = ty0 + (p >> 3), xx = tx0 + (p & 7);                                 \
        int base = rb[p];                                                           \
        float r00 = rw[0][p], r01 = rw[1][p], r10 = rw[2][p], r11 = rw[3][p];       \
        const float* A = &a4t[bb][0];                                               \
        float sdy = A[(2*k)*16+base]*r00 + A[(2*k)*16+base+1]*r01                   \
                  + A[(2*k)*16+base+4]*r10 + A[(2*k)*16+base+5]*r11;                \
        float sdx = A[(2*k+1)*16+base]*r00 + A[(2*k+1)*16+base+1]*r01               \
                  + A[(2*k+1)*16+base+4]*r10 + A[(2*k+1)*16+base+5]*r11;            \
        float sm  = A[(18+k)*16+base]*r00 + A[(18+k)*16+base+1]*r01                 \
                  + A[(18+k)*16+base+4]*r10 + A[(18+k)*16+base+5]*r11;              \
        float dyv = 5.f * tanh_fast(sdy) + flds[bb][p];                             \
        float dxv = 5.f * tanh_fast(sdx) + flds[bb][64 + p];                        \
        float m = sigmoid_fast(sm);                                                 \
        float fpy = (float)(y + (k / 3) - 1) + dyv;                                 \
        float fpx = (float)(xx + (k % 3) - 1) + dxv;                                \
        float y0f = floorf(fpy), x0f = floorf(fpx);                                 \
        int gy0 = (int)y0f, gx0 = (int)x0f;                                         \
        int gy1 = gy0 + 1, gx1 = gx0 + 1;                                           \
        float wy = fpy - y0f, wx = fpx - x0f;                                       \
        bool by0 = (unsigned)gy0 < (unsigned)HH, by1 = (unsigned)gy1 < (unsigned)HH;\
        bool bx0 = (unsigned)gx0 < (unsigned)WW, bx1 = (unsigned)gx1 < (unsigned)WW;\
        int y0c = min(max(gy0, 0), HH - 1), y1c = min(max(gy1, 0), HH - 1);         \
        int x0c = min(max(gx0, 0), WW - 1), x1c = min(max(gx1, 0), WW - 1);         \
        float w00 = (by0 && bx0) ? (1.f - wy) * (1.f - wx) * m : 0.f;               \
        float w01 = (by0 && bx1) ? (1.f - wy) * wx * m : 0.f;                       \
        float w10 = (by1 && bx0) ? wy * (1.f - wx) * m : 0.f;                       \
        float w11 = (by1 && bx1) ? wy * wx * m : 0.f;                               \
        uint4 v00 = *reinterpret_cast<const uint4*>(&xgb[(size_t)(y0c * WW + x0c) * 8]); \
        uint4 v01 = *reinterpret_cast<const uint4*>(&xgb[(size_t)(y0c * WW + x1c) * 8]); \
        uint4 v10 = *reinterpret_cast<const uint4*>(&xgb[(size_t)(y1c * WW + x0c) * 8]); \
        uint4 v11 = *reinterpret_cast<const uint4*>(&xgb[(size_t)(y1c * WW + x1c) * 8]); \
        const __half2* h00 = reinterpret_cast<const __half2*>(&v00);                \
        const __half2* h01 = reinterpret_cast<const __half2*>(&v01);                \
        const __half2* h10 = reinterpret_cast<const __half2*>(&v10);                \
        const __half2* h11 = reinterpret_cast<const __half2*>(&v11);                \
        __half hw00 = __float2half_rn(w00), hw01 = __float2half_rn(w01);            \
        __half hw10 = __float2half_rn(w10), hw11 = __float2half_rn(w11);            \
        __half2 W00{hw00, hw00}, W01{hw01, hw01}, W10{hw10, hw10}, W11{hw11, hw11}; \
        union { __half2 h2[4]; uint4 u4; } uu;                                      \
        _Pragma("unroll")                                                           \
        for (int cc = 0; cc < 4; ++cc)                                              \
            uu.h2[cc] = __hfma2(h00[cc], W00, __hfma2(h01[cc], W01,                 \
                        __hfma2(h10[cc], W10, __hmul2(h11[cc], W11))));             \
        *reinterpret_cast<uint4*>(&val[bb][p * 104 + k * 8]) = uu.u4;               \
    }                                                                               \
} while (0)

    STAGE(0, 0);
    __syncthreads();

    for (int g = 0; g < DG_; ++g) {
        const int buf = g & 1;
        if (g < 15) STAGE(g + 1, buf ^ 1);
        PH12(g, buf);
        __syncthreads();
        const u16* wg = wA + (size_t)(og * 16) * 1536 + g * 96;
        __builtin_amdgcn_s_setprio(1);
#pragma unroll
        for (int kb = 0; kb < 3; ++kb) {
            f16x8 a = *reinterpret_cast<const f16x8*>(wg + (size_t)l15 * 1536 + kb * 32 + l4 * 8);
#pragma unroll
            for (int nf = 0; nf < 4; ++nf) {
                int row = nf * 16 + l15;
                f16x8 bfrag = *reinterpret_cast<const f16x8*>(
                    &val[buf][row * 104 + kb * 32 + l4 * 8]);
                acc[nf] = __builtin_amdgcn_mfma_f32_16x16x32_f16(a, bfrag, acc[nf], 0, 0, 0);
            }
        }
        __builtin_amdgcn_s_setprio(0);
    }
#undef STAGE
#undef PH12
    // epilogue: D col=lane&15 (pixel), row=(lane>>4)*4+reg (oc within 16)
#pragma unroll
    for (int nf = 0; nf < 4; ++nf) {
        int pix = nf * 16 + l15;
        int py = ty0 + (pix >> 3), px = tx0 + (pix & 7);
#pragma unroll
        for (int r = 0; r < 4; ++r) {
            int o = og * 16 + l4 * 4 + r;
            out[((size_t)(b * COUT_D + o) * HH + py) * WW + px] = acc[nf][r] + bias[o];
        }
    }
}

extern "C" void kernel_launch(void* const* d_in, const int* in_sizes, int n_in,
                              void* d_out, int out_size, void* d_ws, size_t ws_size,
                              hipStream_t stream) {
    const float* x    = (const float*)d_in[0];
    const float* flow = (const float*)d_in[1];
    const float* addf = (const float*)d_in[2];
    const float* w1   = (const float*)d_in[3];
    const float* b1   = (const float*)d_in[4];
    const float* w2   = (const float*)d_in[5];
    const float* b2   = (const float*)d_in[6];
    const float* w3   = (const float*)d_in[7];
    const float* b3   = (const float*)d_in[8];
    const float* w4   = (const float*)d_in[9];
    const float* b4   = (const float*)d_in[10];
    const float* wgt  = (const float*)d_in[11];
    const float* bias = (const float*)d_in[12];
    float* out = (float*)d_out;
    float* ws = (float*)d_ws;

    u16*  pool_t = (u16*)ws;                         // 1,474,560 u16
    u16*  c1     = pool_t + 1474560;                 // 589,824 u16
    u16*  c2     = c1 + 589824;                      // 589,824 u16
    u16*  c3     = c1;                               // alias (c1 dead after conv2)
    float* a4    = (float*)(c2 + 589824);            // 1,990,656 f32
    u16*  wq1    = (u16*)(a4 + 1990656);             // 184,320 u16
    u16*  wq2    = wq1 + 184320;                     // 73,728
    u16*  wq3    = wq2 + 73728;                      // 73,728
    u16*  wq4    = wq3 + 73728;                      // 516,096
    u16*  wA     = wq4 + 516096;                     // 196,608 (fp16)
    u16*  xg     = wA + 196608;                      // 9,437,184 (fp16)

    mega_prep_kernel<<<11568, 256, 0, stream>>>(w1, w2, w3, w4, wgt, x, flow, addf,
                                                wq1, wq2, wq3, wq4, wA, xg, pool_t);

    conv_ks<160, 12, 23, 34, 45, true><<<dim3(144, 1, 2), 1024, 0, stream>>>(pool_t, wq1, b1, c1);
    conv_ks<64,  5,  10, 14, 18, true><<<dim3(144, 1, 2), 1024, 0, stream>>>(c1, wq2, b2, c2);
    conv_ks<64,  5,  10, 14, 18, true><<<dim3(144, 1, 2), 1024, 0, stream>>>(c2, wq3, b3, c3);
    conv_mfma<64, 432, 448, false><<<dim3(144, 7, 2), 256, 0, stream>>>(c3, wq4, b4, a4);

    deform_mfma<<<dim3(576, 2), 512, 0, stream>>>(xg, flow, a4, wA, bias, out);
}